// Round 4
// baseline (2157.306 us; speedup 1.0000x reference)
//
#include <hip/hip_runtime.h>
#include <hip/hip_fp16.h>
#include <stdint.h>

typedef _Float16 f16;
typedef _Float16 f16x4 __attribute__((ext_vector_type(4)));
typedef _Float16 f16x8 __attribute__((ext_vector_type(8)));
typedef float f32x4 __attribute__((ext_vector_type(4)));
typedef unsigned long long u64;

#define N_TOK 8192
#define VOCAB 8192
#define DIM   4096
#define DELTA 1.5f

// ---------------------------------------------------------------------------
__device__ __forceinline__ void gload16(const f16* g, void* l) {
    __builtin_amdgcn_global_load_lds(
        (const __attribute__((address_space(1))) unsigned int*)(uintptr_t)g,
        (__attribute__((address_space(3))) unsigned int*)(uintptr_t)l,
        16, 0, 0);
}

__device__ __forceinline__ float keyinv(unsigned k) {
    unsigned b = (k & 0x80000000u) ? (k ^ 0x80000000u) : ~k;
    return __uint_as_float(b);
}

__device__ __forceinline__ void ins2(u64& k1, u64& k2, u64 v) {
    if (v < k1) { k2 = k1; k1 = v; }
    else if (v < k2) { k2 = v; }
}

// ---------------------------------------------------------------------------
// K_pack: fp16 hi-plane of inputs/embedding; embedding norms (f64 acc); zero counts.
__global__ __launch_bounds__(256) void k_pack(const float* __restrict__ inputs,
                                              const float* __restrict__ embedding,
                                              f16* __restrict__ apk, f16* __restrict__ bpk,
                                              float* __restrict__ enorms,
                                              int* __restrict__ counts) {
    int b = blockIdx.x, t = threadIdx.x;
    bool isB = b >= N_TOK;
    int row = isB ? b - N_TOK : b;
    const float* src = (isB ? embedding : inputs) + (size_t)row * DIM;
    f16* dst = (isB ? bpk : apk) + (size_t)row * DIM;
    double nrm = 0.0;
#pragma unroll
    for (int k = 0; k < 4; k++) {
        int d0 = t * 4 + 1024 * k;
        float4 v = *(const float4*)(src + d0);
        float xs[4] = {v.x, v.y, v.z, v.w};
        f16x4 hv;
#pragma unroll
        for (int u = 0; u < 4; u++) {
            hv[u] = (f16)xs[u];
            nrm += (double)xs[u] * (double)xs[u];
        }
        *(f16x4*)(dst + d0) = hv;
    }
    if (isB) {
        __shared__ double red[256];
        red[t] = nrm;
        __syncthreads();
        for (int off = 128; off > 0; off >>= 1) {
            if (t < off) red[t] += red[t + off];
            __syncthreads();
        }
        if (t == 0) {
            enorms[row] = (float)red[0];
            counts[row] = 0;
        }
    }
}

// ---------------------------------------------------------------------------
// K_gemm: approx S = x·e (hi-only fp16 MFMA). m97-proven structure: 128x128
// tile, BK=64, 4 waves, SINGLE-buffered 32KB LDS, stage->sync->compute->sync.
// 4 blocks/CU co-resident do the latency hiding (m114). XOR-swizzled LDS via
// pre-swizzled global source (dest linear) + swizzled reads.
// Epilogue: top-2 (key|col) per (row, 64-col slice).
__global__ __launch_bounds__(256, 4) void k_gemm(const f16* __restrict__ apk,
                                                 const f16* __restrict__ bpk,
                                                 const float* __restrict__ enorms,
                                                 u64* __restrict__ cand) {
    __shared__ alignas(16) char lds[32768];   // A 16KB | B 16KB
    int wg = blockIdx.x;
    wg = (wg & 7) * 512 + (wg >> 3);          // XCD swizzle (4096 % 8 == 0)
    int bm = wg >> 6, bn = wg & 63;
    int tid = threadIdx.x;
    int lane = tid & 63, wid = tid >> 6;
    int wm = wid >> 1, wn = wid & 1;

    // staging: 8 issues/thread/K-step (4 A + 4 B); pre-swizzled source
    const f16* srcs[8];
    unsigned lof[8];
#pragma unroll
    for (int e = 0; e < 8; e++) {
        int tile = e >> 2, q = e & 3;
        int s = q * 256 + tid;                 // 16B slot 0..1023 within tile
        int r = s >> 3;                        // row 0..127
        int c8 = (s & 7) ^ (r & 7);            // inverse swizzle on source
        int row = (tile ? bn : bm) * 128 + r;
        srcs[e] = (tile ? bpk : apk) + (size_t)row * DIM + c8 * 8;
        lof[e] = tile * 16384 + q * 4096 + wid * 1024;   // + lane*16 by HW
    }

    f32x4 acc[4][4];
#pragma unroll
    for (int m = 0; m < 4; m++)
#pragma unroll
        for (int n = 0; n < 4; n++) acc[m][n] = (f32x4){0.f, 0.f, 0.f, 0.f};

    for (int kt = 0; kt < 64; ++kt) {
#pragma unroll
        for (int e = 0; e < 8; e++) { gload16(srcs[e], &lds[lof[e]]); srcs[e] += 64; }
        __syncthreads();   // drains vmcnt -> tiles ready
#pragma unroll
        for (int kk = 0; kk < 2; kk++) {
            f16x8 ah[4], bh[4];
            int cbyte = kk * 64 + (lane >> 4) * 16;
#pragma unroll
            for (int m = 0; m < 4; m++) {
                int r = wm * 64 + m * 16 + (lane & 15);
                ah[m] = *(const f16x8*)&lds[r * 128 + (cbyte ^ ((r & 7) << 4))];
            }
#pragma unroll
            for (int n = 0; n < 4; n++) {
                int r = wn * 64 + n * 16 + (lane & 15);
                bh[n] = *(const f16x8*)&lds[16384 + r * 128 + (cbyte ^ ((r & 7) << 4))];
            }
#pragma unroll
            for (int m = 0; m < 4; m++)
#pragma unroll
                for (int n = 0; n < 4; n++)
                    acc[m][n] = __builtin_amdgcn_mfma_f32_16x16x32_f16(ah[m], bh[n], acc[m][n], 0, 0, 0);
        }
        __syncthreads();   // readers done before next stage overwrites
    }

    // epilogue: approx dist = ||e||^2 - 2S; keep 2 smallest per (row, 64-col slice)
    float en[4];
    int colb = bn * 128 + wn * 64 + (lane & 15);
#pragma unroll
    for (int n = 0; n < 4; n++) en[n] = enorms[colb + n * 16];
#pragma unroll
    for (int m = 0; m < 4; m++) {
#pragma unroll
        for (int reg = 0; reg < 4; reg++) {
            u64 k1 = ~0ull, k2 = ~0ull;
#pragma unroll
            for (int n = 0; n < 4; n++) {
                float d = en[n] - 2.0f * acc[m][n][reg];
                unsigned b = __float_as_uint(d);
                unsigned key = (b & 0x80000000u) ? ~b : (b | 0x80000000u);
                ins2(k1, k2, ((u64)key << 32) | (unsigned)(colb + n * 16));
            }
#pragma unroll
            for (int msk = 1; msk < 16; msk <<= 1) {
                u64 o1 = __shfl_xor(k1, msk, 64);
                u64 o2 = __shfl_xor(k2, msk, 64);
                ins2(k1, k2, o1);
                ins2(k1, k2, o2);
            }
            if ((lane & 15) == 0) {
                int rowg = bm * 128 + wm * 64 + m * 16 + ((lane >> 4) << 2) + reg;
                size_t slot = ((size_t)rowg * 64 + bn) * 2 + wn;
                ulonglong2 v; v.x = k1; v.y = k2;
                *(ulonglong2*)&cand[slot * 2] = v;
            }
        }
    }
}

// ---------------------------------------------------------------------------
// K_cand: per token, min over 256 stored entries; collect candidates within
// DELTA; exact f32 recheck; fused quantize-copy + loss partial + count.
// Reductions: wave-shuffle + 4-wave LDS combine (2 barriers, not 8-step trees).
__global__ __launch_bounds__(256) void k_cand(const u64* __restrict__ cand,
                                              const float* __restrict__ enorms,
                                              const float* __restrict__ inputs,
                                              const float* __restrict__ embedding,
                                              float* __restrict__ o_idx,
                                              float* __restrict__ o_quant,
                                              float* __restrict__ partials,
                                              int* __restrict__ counts) {
    int tok = blockIdx.x, t = threadIdx.x;
    int lane = t & 63, w = t >> 6;
    __shared__ u64 redu[4];
    __shared__ float redf[4];
    __shared__ int clist[64];
    __shared__ int s_cnt;
    if (t == 0) s_cnt = 0;
    u64 e = cand[(size_t)tok * 256 + t];
    u64 v = e;
#pragma unroll
    for (int msk = 1; msk < 64; msk <<= 1) {
        u64 o = __shfl_xor(v, msk, 64);
        if (o < v) v = o;
    }
    if (lane == 0) redu[w] = v;
    __syncthreads();
    u64 m01 = redu[0] < redu[1] ? redu[0] : redu[1];
    u64 m23 = redu[2] < redu[3] ? redu[2] : redu[3];
    u64 mall = m01 < m23 ? m01 : m23;
    float dmin = keyinv((unsigned)(mall >> 32));
    float myd = keyinv((unsigned)(e >> 32));
    if (myd <= dmin + DELTA) {
        int p = atomicAdd(&s_cnt, 1);
        if (p < 64) clist[p] = (int)(unsigned)(e & 0xffffffffu);
    }
    __syncthreads();
    int nc = min(s_cnt, 64);

    const float* xrow = inputs + (size_t)tok * DIM;
    float xr[16];
#pragma unroll
    for (int k = 0; k < 16; k++) xr[k] = xrow[t + 256 * k];

    float best = 3.4e38f;
    int bcol = 0x7fffffff;
    for (int i = 0; i < nc; i++) {
        int c = clist[i];
        const float* erow = embedding + (size_t)c * DIM;
        float p = 0.f;
#pragma unroll
        for (int k = 0; k < 16; k++) p += xr[k] * erow[t + 256 * k];
#pragma unroll
        for (int msk = 1; msk < 64; msk <<= 1) p += __shfl_xor(p, msk, 64);
        if (lane == 0) redf[w] = p;
        __syncthreads();
        float dot = (redf[0] + redf[1]) + (redf[2] + redf[3]);
        float dist = enorms[c] - 2.0f * dot;
        __syncthreads();
        if (dist < best || (dist == best && c < bcol)) { best = dist; bcol = c; }
    }
    // all threads agree on bcol (identical reduced values)
    const float* eb = embedding + (size_t)bcol * DIM;
    float* qrow = o_quant + (size_t)tok * DIM;
    float ls = 0.f;
#pragma unroll
    for (int k = 0; k < 16; k++) {
        int d = t + 256 * k;
        float q = eb[d];
        qrow[d] = q;
        float df = q - xr[k];
        ls += df * df;
    }
#pragma unroll
    for (int msk = 1; msk < 64; msk <<= 1) ls += __shfl_xor(ls, msk, 64);
    if (lane == 0) redf[w] = ls;
    __syncthreads();
    if (t == 0) {
        partials[tok] = (redf[0] + redf[1]) + (redf[2] + redf[3]);
        o_idx[tok] = (float)bcol;
        atomicAdd(&counts[bcol], 1);
    }
}

// ---------------------------------------------------------------------------
__global__ __launch_bounds__(1024) void k_cs(const int* __restrict__ counts,
                                             const float* __restrict__ ema_cs,
                                             float* __restrict__ o_ncs,
                                             float* __restrict__ o_perp) {
    __shared__ float red[1024];
    int t = threadIdx.x;
    float pre[8];
    float psum = 0.f, esum = 0.f;
#pragma unroll
    for (int k = 0; k < 8; k++) {
        int j = t * 8 + k;
        float c = (float)counts[j];
        float p = ema_cs[j] * 0.99f + 0.01f * c;
        pre[k] = p;
        psum += p;
        float ap = c * (1.0f / 8192.0f);
        esum += ap * logf(ap + 1e-10f);
    }
    red[t] = psum;
    __syncthreads();
    for (int off = 512; off > 0; off >>= 1) {
        if (t < off) red[t] += red[t + off];
        __syncthreads();
    }
    float n = red[0];
    __syncthreads();
    red[t] = esum;
    __syncthreads();
    for (int off = 512; off > 0; off >>= 1) {
        if (t < off) red[t] += red[t + off];
        __syncthreads();
    }
    if (t == 0) o_perp[0] = expf(-red[0]);
    float scale = n / (n + (float)VOCAB * 1e-5f);
#pragma unroll
    for (int k = 0; k < 8; k++) {
        int j = t * 8 + k;
        o_ncs[j] = (pre[k] + 1e-5f) * scale;
    }
}

// ---------------------------------------------------------------------------
__global__ __launch_bounds__(1024) void k_loss(const float* __restrict__ partials,
                                               float* __restrict__ o_loss) {
    __shared__ float red[1024];
    int t = threadIdx.x;
    float s = 0.f;
#pragma unroll
    for (int k = 0; k < 8; k++) s += partials[t * 8 + k];
    red[t] = s;
    __syncthreads();
    for (int off = 512; off > 0; off >>= 1) {
        if (t < off) red[t] += red[t + off];
        __syncthreads();
    }
    if (t == 0) o_loss[0] = 0.25f * red[0] / ((float)N_TOK * (float)DIM);
}

// ---------------------------------------------------------------------------
// K_ema: block j owns code j; ordered token list (deterministic) then EMA math.
__global__ __launch_bounds__(256) void k_ema(const float* __restrict__ o_idx,
                                             const float* __restrict__ inputs,
                                             const float* __restrict__ ema_w,
                                             const float* __restrict__ o_ncs,
                                             float* __restrict__ o_neww,
                                             float* __restrict__ o_newemb) {
    int j = blockIdx.x, t = threadIdx.x;
    __shared__ int scan[256];
    __shared__ int list[256];
    __shared__ int s_total;
    int c = 0;
    for (int k = 0; k < 32; k++) {
        int tok = t * 32 + k;
        if ((int)o_idx[tok] == j) c++;
    }
    scan[t] = c;
    __syncthreads();
    for (int off = 1; off < 256; off <<= 1) {
        int add = (t >= off) ? scan[t - off] : 0;
        __syncthreads();
        scan[t] += add;
        __syncthreads();
    }
    int excl = scan[t] - c;
    if (t == 255) s_total = scan[255];
    __syncthreads();
    int pos = excl;
    for (int k = 0; k < 32; k++) {
        int tok = t * 32 + k;
        if ((int)o_idx[tok] == j && pos < 256) list[pos++] = tok;
    }
    __syncthreads();
    int total = s_total;
    float nc = o_ncs[j];
    size_t rowoff = (size_t)j * DIM;
#pragma unroll
    for (int k = 0; k < 16; k++) {
        int d = t + 256 * k;
        float s = 0.f;
        for (int q = 0; q < total; q++) s += inputs[(size_t)list[q] * DIM + d];
        float w = ema_w[rowoff + d] * 0.99f + 0.01f * s;
        o_neww[rowoff + d] = w;
        o_newemb[rowoff + d] = w / nc;
    }
}

// ---------------------------------------------------------------------------
extern "C" void kernel_launch(void* const* d_in, const int* in_sizes, int n_in,
                              void* d_out, int out_size, void* d_ws, size_t ws_size,
                              hipStream_t stream) {
    const float* inputs    = (const float*)d_in[0];
    const float* embedding = (const float*)d_in[1];
    const float* ema_w     = (const float*)d_in[2];
    const float* ema_cs    = (const float*)d_in[3];

    float* out = (float*)d_out;
    char* base = (char*)d_out;

    // scratch carved from d_out (lifetime-checked, layout proven in round 2)
    f16* apk        = (f16*)(base);                    // [0, 64M)
    f16* bpk        = (f16*)(base + 67108864);         // [64M, 128M)
    u64* cand       = (u64*)(base + 167772160);        // 16 MB, dead after k_cand
    float* enorms   = (float*)(base + 184549376);      // 32 KB, dead after k_cand
    int* counts     = (int*)(base + 184582144);        // 32 KB, dead after k_cs
    float* partials = (float*)(base + 184614912);      // 32 KB, dead after k_loss

    // output regions (element offsets, return order)
    float* o_loss   = out;                 // [1]
    float* o_quant  = out + 1;             // [8192*4096]
    float* o_perp   = out + 33554433;      // [1]
    float* o_idx    = out + 33554434;      // [8192]
    float* o_ncs    = out + 33562626;      // [8192]
    float* o_neww   = out + 33570818;      // [8192*4096]
    float* o_newemb = out + 67125250;      // [8192*4096]

    k_pack<<<dim3(N_TOK + VOCAB), dim3(256), 0, stream>>>(inputs, embedding, apk, bpk,
                                                          enorms, counts);
    k_gemm<<<dim3(4096), dim3(256), 0, stream>>>(apk, bpk, enorms, cand);
    k_cand<<<dim3(N_TOK), dim3(256), 0, stream>>>(cand, enorms, inputs, embedding,
                                                  o_idx, o_quant, partials, counts);
    k_cs<<<dim3(1), dim3(1024), 0, stream>>>(counts, ema_cs, o_ncs, o_perp);
    k_loss<<<dim3(1), dim3(1024), 0, stream>>>(partials, o_loss);
    k_ema<<<dim3(VOCAB), dim3(256), 0, stream>>>(o_idx, inputs, ema_w, o_ncs, o_neww, o_newemb);
}

// Round 5
// 1993.520 us; speedup vs baseline: 1.0822x; 1.0822x over previous
//
#include <hip/hip_runtime.h>
#include <hip/hip_fp16.h>
#include <stdint.h>

typedef _Float16 f16;
typedef _Float16 f16x4 __attribute__((ext_vector_type(4)));
typedef _Float16 f16x8 __attribute__((ext_vector_type(8)));
typedef float f32x4 __attribute__((ext_vector_type(4)));
typedef unsigned long long u64;

#define N_TOK 8192
#define VOCAB 8192
#define DIM   4096
#define DELTA 1.5f

// ---------------------------------------------------------------------------
__device__ __forceinline__ void gload16(const f16* g, void* l) {
    __builtin_amdgcn_global_load_lds(
        (const __attribute__((address_space(1))) unsigned int*)(uintptr_t)g,
        (__attribute__((address_space(3))) unsigned int*)(uintptr_t)l,
        16, 0, 0);
}

__device__ __forceinline__ float keyinv(unsigned k) {
    unsigned b = (k & 0x80000000u) ? (k ^ 0x80000000u) : ~k;
    return __uint_as_float(b);
}

__device__ __forceinline__ void ins2(u64& k1, u64& k2, u64 v) {
    if (v < k1) { k2 = k1; k1 = v; }
    else if (v < k2) { k2 = v; }
}

// ---------------------------------------------------------------------------
// K_pack: fp16 hi-plane of inputs/embedding; embedding norms (f64 acc); zero counts.
__global__ __launch_bounds__(256) void k_pack(const float* __restrict__ inputs,
                                              const float* __restrict__ embedding,
                                              f16* __restrict__ apk, f16* __restrict__ bpk,
                                              float* __restrict__ enorms,
                                              int* __restrict__ counts) {
    int b = blockIdx.x, t = threadIdx.x;
    bool isB = b >= N_TOK;
    int row = isB ? b - N_TOK : b;
    const float* src = (isB ? embedding : inputs) + (size_t)row * DIM;
    f16* dst = (isB ? bpk : apk) + (size_t)row * DIM;
    double nrm = 0.0;
#pragma unroll
    for (int k = 0; k < 4; k++) {
        int d0 = t * 4 + 1024 * k;
        float4 v = *(const float4*)(src + d0);
        float xs[4] = {v.x, v.y, v.z, v.w};
        f16x4 hv;
#pragma unroll
        for (int u = 0; u < 4; u++) {
            hv[u] = (f16)xs[u];
            nrm += (double)xs[u] * (double)xs[u];
        }
        *(f16x4*)(dst + d0) = hv;
    }
    if (isB) {
        __shared__ double red[256];
        red[t] = nrm;
        __syncthreads();
        for (int off = 128; off > 0; off >>= 1) {
            if (t < off) red[t] += red[t + off];
            __syncthreads();
        }
        if (t == 0) {
            enorms[row] = (float)red[0];
            counts[row] = 0;
        }
    }
}

// ---------------------------------------------------------------------------
// K_gemm: approx S = x·e (hi-only fp16 MFMA). m97 structure: 128x128 tile,
// BK=64, 4 waves, single-buffered 32KB LDS, stage->sync->compute->sync.
// NO occupancy pin: R4's __launch_bounds__(256,4) capped VGPR at 64 and
// spilled the accumulator (WRITE_SIZE 24->129 MB). Compiler-chosen VGPR
// (~3 blocks/CU) is the m97-measured regime; co-resident blocks hide the
// barrier drain (m114). XOR-swizzled LDS via pre-swizzled global source.
// Epilogue: top-2 (key|col) per (row, 64-col slice).
__global__ __launch_bounds__(256) void k_gemm(const f16* __restrict__ apk,
                                              const f16* __restrict__ bpk,
                                              const float* __restrict__ enorms,
                                              u64* __restrict__ cand) {
    __shared__ alignas(16) char lds[32768];   // A 16KB | B 16KB
    int wg = blockIdx.x;
    wg = (wg & 7) * 512 + (wg >> 3);          // XCD swizzle (4096 % 8 == 0)
    int bm = wg >> 6, bn = wg & 63;
    int tid = threadIdx.x;
    int lane = tid & 63, wid = tid >> 6;
    int wm = wid >> 1, wn = wid & 1;

    // staging: 8 issues/thread/K-step (4 A + 4 B); pre-swizzled source
    const f16* srcs[8];
    unsigned lof[8];
#pragma unroll
    for (int e = 0; e < 8; e++) {
        int tile = e >> 2, q = e & 3;
        int s = q * 256 + tid;                 // 16B slot 0..1023 within tile
        int r = s >> 3;                        // row 0..127
        int c8 = (s & 7) ^ (r & 7);            // inverse swizzle on source
        int row = (tile ? bn : bm) * 128 + r;
        srcs[e] = (tile ? bpk : apk) + (size_t)row * DIM + c8 * 8;
        lof[e] = tile * 16384 + q * 4096 + wid * 1024;   // + lane*16 by HW
    }

    f32x4 acc[4][4];
#pragma unroll
    for (int m = 0; m < 4; m++)
#pragma unroll
        for (int n = 0; n < 4; n++) acc[m][n] = (f32x4){0.f, 0.f, 0.f, 0.f};

    for (int kt = 0; kt < 64; ++kt) {
#pragma unroll
        for (int e = 0; e < 8; e++) { gload16(srcs[e], &lds[lof[e]]); srcs[e] += 64; }
        __syncthreads();   // drains vmcnt -> tiles ready
#pragma unroll
        for (int kk = 0; kk < 2; kk++) {
            f16x8 ah[4], bh[4];
            int cbyte = kk * 64 + (lane >> 4) * 16;
#pragma unroll
            for (int m = 0; m < 4; m++) {
                int r = wm * 64 + m * 16 + (lane & 15);
                ah[m] = *(const f16x8*)&lds[r * 128 + (cbyte ^ ((r & 7) << 4))];
            }
#pragma unroll
            for (int n = 0; n < 4; n++) {
                int r = wn * 64 + n * 16 + (lane & 15);
                bh[n] = *(const f16x8*)&lds[16384 + r * 128 + (cbyte ^ ((r & 7) << 4))];
            }
#pragma unroll
            for (int m = 0; m < 4; m++)
#pragma unroll
                for (int n = 0; n < 4; n++)
                    acc[m][n] = __builtin_amdgcn_mfma_f32_16x16x32_f16(ah[m], bh[n], acc[m][n], 0, 0, 0);
        }
        __syncthreads();   // readers done before next stage overwrites
    }

    // epilogue: approx dist = ||e||^2 - 2S; keep 2 smallest per (row, 64-col slice)
    float en[4];
    int colb = bn * 128 + wn * 64 + (lane & 15);
#pragma unroll
    for (int n = 0; n < 4; n++) en[n] = enorms[colb + n * 16];
#pragma unroll
    for (int m = 0; m < 4; m++) {
#pragma unroll
        for (int reg = 0; reg < 4; reg++) {
            u64 k1 = ~0ull, k2 = ~0ull;
#pragma unroll
            for (int n = 0; n < 4; n++) {
                float d = en[n] - 2.0f * acc[m][n][reg];
                unsigned b = __float_as_uint(d);
                unsigned key = (b & 0x80000000u) ? ~b : (b | 0x80000000u);
                ins2(k1, k2, ((u64)key << 32) | (unsigned)(colb + n * 16));
            }
#pragma unroll
            for (int msk = 1; msk < 16; msk <<= 1) {
                u64 o1 = __shfl_xor(k1, msk, 64);
                u64 o2 = __shfl_xor(k2, msk, 64);
                ins2(k1, k2, o1);
                ins2(k1, k2, o2);
            }
            if ((lane & 15) == 0) {
                int rowg = bm * 128 + wm * 64 + m * 16 + ((lane >> 4) << 2) + reg;
                size_t slot = ((size_t)rowg * 64 + bn) * 2 + wn;
                ulonglong2 v; v.x = k1; v.y = k2;
                *(ulonglong2*)&cand[slot * 2] = v;
            }
        }
    }
}

// ---------------------------------------------------------------------------
// K_cand: per token, min over 256 stored entries; collect candidates within
// DELTA; exact f32 recheck; fused quantize-copy + loss partial + count.
__global__ __launch_bounds__(256) void k_cand(const u64* __restrict__ cand,
                                              const float* __restrict__ enorms,
                                              const float* __restrict__ inputs,
                                              const float* __restrict__ embedding,
                                              float* __restrict__ o_idx,
                                              float* __restrict__ o_quant,
                                              float* __restrict__ partials,
                                              int* __restrict__ counts) {
    int tok = blockIdx.x, t = threadIdx.x;
    int lane = t & 63, w = t >> 6;
    __shared__ u64 redu[4];
    __shared__ float redf[4];
    __shared__ int clist[64];
    __shared__ int s_cnt;
    if (t == 0) s_cnt = 0;
    u64 e = cand[(size_t)tok * 256 + t];
    u64 v = e;
#pragma unroll
    for (int msk = 1; msk < 64; msk <<= 1) {
        u64 o = __shfl_xor(v, msk, 64);
        if (o < v) v = o;
    }
    if (lane == 0) redu[w] = v;
    __syncthreads();
    u64 m01 = redu[0] < redu[1] ? redu[0] : redu[1];
    u64 m23 = redu[2] < redu[3] ? redu[2] : redu[3];
    u64 mall = m01 < m23 ? m01 : m23;
    float dmin = keyinv((unsigned)(mall >> 32));
    float myd = keyinv((unsigned)(e >> 32));
    if (myd <= dmin + DELTA) {
        int p = atomicAdd(&s_cnt, 1);
        if (p < 64) clist[p] = (int)(unsigned)(e & 0xffffffffu);
    }
    __syncthreads();
    int nc = min(s_cnt, 64);

    const float* xrow = inputs + (size_t)tok * DIM;
    float xr[16];
#pragma unroll
    for (int k = 0; k < 16; k++) xr[k] = xrow[t + 256 * k];

    float best = 3.4e38f;
    int bcol = 0x7fffffff;
    for (int i = 0; i < nc; i++) {
        int c = clist[i];
        const float* erow = embedding + (size_t)c * DIM;
        float p = 0.f;
#pragma unroll
        for (int k = 0; k < 16; k++) p += xr[k] * erow[t + 256 * k];
#pragma unroll
        for (int msk = 1; msk < 64; msk <<= 1) p += __shfl_xor(p, msk, 64);
        if (lane == 0) redf[w] = p;
        __syncthreads();
        float dot = (redf[0] + redf[1]) + (redf[2] + redf[3]);
        float dist = enorms[c] - 2.0f * dot;
        __syncthreads();
        if (dist < best || (dist == best && c < bcol)) { best = dist; bcol = c; }
    }
    // all threads agree on bcol (identical reduced values)
    const float* eb = embedding + (size_t)bcol * DIM;
    float* qrow = o_quant + (size_t)tok * DIM;
    float ls = 0.f;
#pragma unroll
    for (int k = 0; k < 16; k++) {
        int d = t + 256 * k;
        float q = eb[d];
        qrow[d] = q;
        float df = q - xr[k];
        ls += df * df;
    }
#pragma unroll
    for (int msk = 1; msk < 64; msk <<= 1) ls += __shfl_xor(ls, msk, 64);
    if (lane == 0) redf[w] = ls;
    __syncthreads();
    if (t == 0) {
        partials[tok] = (redf[0] + redf[1]) + (redf[2] + redf[3]);
        o_idx[tok] = (float)bcol;
        atomicAdd(&counts[bcol], 1);
    }
}

// ---------------------------------------------------------------------------
__global__ __launch_bounds__(1024) void k_cs(const int* __restrict__ counts,
                                             const float* __restrict__ ema_cs,
                                             float* __restrict__ o_ncs,
                                             float* __restrict__ o_perp) {
    __shared__ float red[1024];
    int t = threadIdx.x;
    float pre[8];
    float psum = 0.f, esum = 0.f;
#pragma unroll
    for (int k = 0; k < 8; k++) {
        int j = t * 8 + k;
        float c = (float)counts[j];
        float p = ema_cs[j] * 0.99f + 0.01f * c;
        pre[k] = p;
        psum += p;
        float ap = c * (1.0f / 8192.0f);
        esum += ap * logf(ap + 1e-10f);
    }
    red[t] = psum;
    __syncthreads();
    for (int off = 512; off > 0; off >>= 1) {
        if (t < off) red[t] += red[t + off];
        __syncthreads();
    }
    float n = red[0];
    __syncthreads();
    red[t] = esum;
    __syncthreads();
    for (int off = 512; off > 0; off >>= 1) {
        if (t < off) red[t] += red[t + off];
        __syncthreads();
    }
    if (t == 0) o_perp[0] = expf(-red[0]);
    float scale = n / (n + (float)VOCAB * 1e-5f);
#pragma unroll
    for (int k = 0; k < 8; k++) {
        int j = t * 8 + k;
        o_ncs[j] = (pre[k] + 1e-5f) * scale;
    }
}

// ---------------------------------------------------------------------------
__global__ __launch_bounds__(1024) void k_loss(const float* __restrict__ partials,
                                               float* __restrict__ o_loss) {
    __shared__ float red[1024];
    int t = threadIdx.x;
    float s = 0.f;
#pragma unroll
    for (int k = 0; k < 8; k++) s += partials[t * 8 + k];
    red[t] = s;
    __syncthreads();
    for (int off = 512; off > 0; off >>= 1) {
        if (t < off) red[t] += red[t + off];
        __syncthreads();
    }
    if (t == 0) o_loss[0] = 0.25f * red[0] / ((float)N_TOK * (float)DIM);
}

// ---------------------------------------------------------------------------
// K_ema: block j owns code j; ordered token list (deterministic) then EMA math.
__global__ __launch_bounds__(256) void k_ema(const float* __restrict__ o_idx,
                                             const float* __restrict__ inputs,
                                             const float* __restrict__ ema_w,
                                             const float* __restrict__ o_ncs,
                                             float* __restrict__ o_neww,
                                             float* __restrict__ o_newemb) {
    int j = blockIdx.x, t = threadIdx.x;
    __shared__ int scan[256];
    __shared__ int list[256];
    __shared__ int s_total;
    int c = 0;
    for (int k = 0; k < 32; k++) {
        int tok = t * 32 + k;
        if ((int)o_idx[tok] == j) c++;
    }
    scan[t] = c;
    __syncthreads();
    for (int off = 1; off < 256; off <<= 1) {
        int add = (t >= off) ? scan[t - off] : 0;
        __syncthreads();
        scan[t] += add;
        __syncthreads();
    }
    int excl = scan[t] - c;
    if (t == 255) s_total = scan[255];
    __syncthreads();
    int pos = excl;
    for (int k = 0; k < 32; k++) {
        int tok = t * 32 + k;
        if ((int)o_idx[tok] == j && pos < 256) list[pos++] = tok;
    }
    __syncthreads();
    int total = s_total;
    float nc = o_ncs[j];
    size_t rowoff = (size_t)j * DIM;
#pragma unroll
    for (int k = 0; k < 16; k++) {
        int d = t + 256 * k;
        float s = 0.f;
        for (int q = 0; q < total; q++) s += inputs[(size_t)list[q] * DIM + d];
        float w = ema_w[rowoff + d] * 0.99f + 0.01f * s;
        o_neww[rowoff + d] = w;
        o_newemb[rowoff + d] = w / nc;
    }
}

// ---------------------------------------------------------------------------
extern "C" void kernel_launch(void* const* d_in, const int* in_sizes, int n_in,
                              void* d_out, int out_size, void* d_ws, size_t ws_size,
                              hipStream_t stream) {
    const float* inputs    = (const float*)d_in[0];
    const float* embedding = (const float*)d_in[1];
    const float* ema_w     = (const float*)d_in[2];
    const float* ema_cs    = (const float*)d_in[3];

    float* out = (float*)d_out;
    char* base = (char*)d_out;

    // scratch carved from d_out (lifetime-checked, layout proven in round 2)
    f16* apk        = (f16*)(base);                    // [0, 64M)
    f16* bpk        = (f16*)(base + 67108864);         // [64M, 128M)
    u64* cand       = (u64*)(base + 167772160);        // 16 MB, dead after k_cand
    float* enorms   = (float*)(base + 184549376);      // 32 KB, dead after k_cand
    int* counts     = (int*)(base + 184582144);        // 32 KB, dead after k_cs
    float* partials = (float*)(base + 184614912);      // 32 KB, dead after k_loss

    // output regions (element offsets, return order)
    float* o_loss   = out;                 // [1]
    float* o_quant  = out + 1;             // [8192*4096]
    float* o_perp   = out + 33554433;      // [1]
    float* o_idx    = out + 33554434;      // [8192]
    float* o_ncs    = out + 33562626;      // [8192]
    float* o_neww   = out + 33570818;      // [8192*4096]
    float* o_newemb = out + 67125250;      // [8192*4096]

    k_pack<<<dim3(N_TOK + VOCAB), dim3(256), 0, stream>>>(inputs, embedding, apk, bpk,
                                                          enorms, counts);
    k_gemm<<<dim3(4096), dim3(256), 0, stream>>>(apk, bpk, enorms, cand);
    k_cand<<<dim3(N_TOK), dim3(256), 0, stream>>>(cand, enorms, inputs, embedding,
                                                  o_idx, o_quant, partials, counts);
    k_cs<<<dim3(1), dim3(1024), 0, stream>>>(counts, ema_cs, o_ncs, o_perp);
    k_loss<<<dim3(1), dim3(1024), 0, stream>>>(partials, o_loss);
    k_ema<<<dim3(VOCAB), dim3(256), 0, stream>>>(o_idx, inputs, ema_w, o_ncs, o_neww, o_newemb);
}

// Round 6
// 1854.583 us; speedup vs baseline: 1.1632x; 1.0749x over previous
//
#include <hip/hip_runtime.h>
#include <hip/hip_fp16.h>
#include <stdint.h>

typedef _Float16 f16;
typedef float f32x4 __attribute__((ext_vector_type(4)));
typedef unsigned long long u64;
typedef long long i64;

#define N_TOK 8192
#define VOCAB 8192
#define DIM   4096
#define DELTA 64.0f

// ---------------------------------------------------------------------------
__device__ __forceinline__ void gload16(const void* g, void* l) {
    __builtin_amdgcn_global_load_lds(
        (const __attribute__((address_space(1))) unsigned int*)(uintptr_t)g,
        (__attribute__((address_space(3))) unsigned int*)(uintptr_t)l,
        16, 0, 0);
}

__device__ __forceinline__ float keyinv(unsigned k) {
    unsigned b = (k & 0x80000000u) ? (k ^ 0x80000000u) : ~k;
    return __uint_as_float(b);
}

__device__ __forceinline__ void ins2(u64& k1, u64& k2, u64 v) {
    if (v < k1) { k2 = k1; k1 = v; }
    else if (v < k2) { k2 = v; }
}

// ---------------------------------------------------------------------------
// K_pack: fp8-e4m3 plane of inputs/embedding; embedding norms (f64 acc); zero counts.
__global__ __launch_bounds__(256) void k_pack(const float* __restrict__ inputs,
                                              const float* __restrict__ embedding,
                                              char* __restrict__ apk, char* __restrict__ bpk,
                                              float* __restrict__ enorms,
                                              int* __restrict__ counts) {
    int b = blockIdx.x, t = threadIdx.x;
    bool isB = b >= N_TOK;
    int row = isB ? b - N_TOK : b;
    const float* src = (isB ? embedding : inputs) + (size_t)row * DIM;
    char* dst = (isB ? bpk : apk) + (size_t)row * DIM;
    double nrm = 0.0;
#pragma unroll
    for (int k = 0; k < 4; k++) {
        int d0 = t * 4 + 1024 * k;
        float4 v = *(const float4*)(src + d0);
        nrm += (double)v.x * v.x + (double)v.y * v.y
             + (double)v.z * v.z + (double)v.w * v.w;
        int packed = 0;
        packed = __builtin_amdgcn_cvt_pk_fp8_f32(v.x, v.y, packed, false);
        packed = __builtin_amdgcn_cvt_pk_fp8_f32(v.z, v.w, packed, true);
        *(int*)(dst + d0) = packed;
    }
    if (isB) {
        __shared__ double red[256];
        red[t] = nrm;
        __syncthreads();
        for (int off = 128; off > 0; off >>= 1) {
            if (t < off) red[t] += red[t + off];
            __syncthreads();
        }
        if (t == 0) {
            enorms[row] = (float)red[0];
            counts[row] = 0;
        }
    }
}

// ---------------------------------------------------------------------------
// K_gemm: approx S = x·e via fp8-e4m3 MFMA (16x16x32_fp8_fp8). m97 structure:
// 128x128 tile, BK=128 fp8 (same 32KB LDS, 2x MFMA per staged byte vs R5),
// 4 waves, single-buffered, stage->sync->compute->sync; ~4 blocks/CU hide
// the barrier drain. 16B-granule XOR swizzle (pre-swizzled source, linear
// LDS dest, swizzled b64 frag reads — balanced 4 accesses/bank).
// Epilogue: top-2 (key|col) per (row, 64-col slice); exact recheck downstream.
__global__ __launch_bounds__(256) void k_gemm(const char* __restrict__ apk,
                                              const char* __restrict__ bpk,
                                              const float* __restrict__ enorms,
                                              u64* __restrict__ cand) {
    __shared__ alignas(16) char lds[32768];   // A 16KB | B 16KB
    int wg = blockIdx.x;
    wg = (wg & 7) * 512 + (wg >> 3);          // XCD swizzle (4096 % 8 == 0)
    int bm = wg >> 6, bn = wg & 63;
    int tid = threadIdx.x;
    int lane = tid & 63, wid = tid >> 6;
    int wm = wid >> 1, wn = wid & 1;

    // staging: 8 issues/thread/K-step (4 A + 4 B); source pre-swizzled at 16B
    const char* srcs[8];
    unsigned lof[8];
#pragma unroll
    for (int e = 0; e < 8; e++) {
        int tile = e >> 2, q = e & 3;
        int s = q * 256 + tid;                 // 16B slot 0..1023 within tile
        int r = s >> 3;                        // row 0..127 (128B rows)
        int c16 = (s & 7) ^ (r & 7);           // inverse swizzle on source
        int row = (tile ? bn : bm) * 128 + r;
        srcs[e] = (tile ? bpk : apk) + (size_t)row * DIM + c16 * 16;
        lof[e] = tile * 16384 + q * 4096 + wid * 1024;   // + lane*16 by HW
    }

    f32x4 acc[4][4];
#pragma unroll
    for (int m = 0; m < 4; m++)
#pragma unroll
        for (int n = 0; n < 4; n++) acc[m][n] = (f32x4){0.f, 0.f, 0.f, 0.f};

    const int g8 = (lane >> 4) * 8;           // byte offset of lane's k-group
    const int ra = wm * 64 + (lane & 15);     // A row base (+ m*16)
    const int rb = wn * 64 + (lane & 15);     // B row base (+ n*16)

    for (int kt = 0; kt < 32; ++kt) {
#pragma unroll
        for (int e = 0; e < 8; e++) { gload16(srcs[e], &lds[lof[e]]); srcs[e] += 128; }
        __syncthreads();   // drains vmcnt -> tiles ready
#pragma unroll
        for (int kk = 0; kk < 4; kk++) {
            int kbyte = kk * 32 + g8;
            i64 ah[4], bh[4];
#pragma unroll
            for (int m = 0; m < 4; m++) {
                int r = ra + m * 16;
                int addr = r * 128 + ((((kbyte >> 4) ^ (r & 7)) << 4) | (kbyte & 15));
                ah[m] = *(const i64*)&lds[addr];
            }
#pragma unroll
            for (int n = 0; n < 4; n++) {
                int r = rb + n * 16;
                int addr = 16384 + r * 128 + ((((kbyte >> 4) ^ (r & 7)) << 4) | (kbyte & 15));
                bh[n] = *(const i64*)&lds[addr];
            }
#pragma unroll
            for (int m = 0; m < 4; m++)
#pragma unroll
                for (int n = 0; n < 4; n++)
                    acc[m][n] = __builtin_amdgcn_mfma_f32_16x16x32_fp8_fp8(ah[m], bh[n], acc[m][n], 0, 0, 0);
        }
        __syncthreads();   // readers done before next stage overwrites
    }

    // epilogue: approx dist = ||e||^2 - 2S; keep 2 smallest per (row, 64-col slice)
    float en[4];
    int colb = bn * 128 + wn * 64 + (lane & 15);
#pragma unroll
    for (int n = 0; n < 4; n++) en[n] = enorms[colb + n * 16];
#pragma unroll
    for (int m = 0; m < 4; m++) {
#pragma unroll
        for (int reg = 0; reg < 4; reg++) {
            u64 k1 = ~0ull, k2 = ~0ull;
#pragma unroll
            for (int n = 0; n < 4; n++) {
                float d = en[n] - 2.0f * acc[m][n][reg];
                unsigned b = __float_as_uint(d);
                unsigned key = (b & 0x80000000u) ? ~b : (b | 0x80000000u);
                ins2(k1, k2, ((u64)key << 32) | (unsigned)(colb + n * 16));
            }
#pragma unroll
            for (int msk = 1; msk < 16; msk <<= 1) {
                u64 o1 = __shfl_xor(k1, msk, 64);
                u64 o2 = __shfl_xor(k2, msk, 64);
                ins2(k1, k2, o1);
                ins2(k1, k2, o2);
            }
            if ((lane & 15) == 0) {
                int rowg = bm * 128 + wm * 64 + m * 16 + ((lane >> 4) << 2) + reg;
                size_t slot = ((size_t)rowg * 64 + bn) * 2 + wn;
                ulonglong2 v; v.x = k1; v.y = k2;
                *(ulonglong2*)&cand[slot * 2] = v;
            }
        }
    }
}

// ---------------------------------------------------------------------------
// K_cand: per token, min over 256 stored entries; collect candidates within
// DELTA; exact f32 recheck; fused quantize-copy + loss partial + count.
__global__ __launch_bounds__(256) void k_cand(const u64* __restrict__ cand,
                                              const float* __restrict__ enorms,
                                              const float* __restrict__ inputs,
                                              const float* __restrict__ embedding,
                                              float* __restrict__ o_idx,
                                              float* __restrict__ o_quant,
                                              float* __restrict__ partials,
                                              int* __restrict__ counts) {
    int tok = blockIdx.x, t = threadIdx.x;
    int lane = t & 63, w = t >> 6;
    __shared__ u64 redu[4];
    __shared__ float redf[4];
    __shared__ int clist[64];
    __shared__ int s_cnt;
    if (t == 0) s_cnt = 0;
    u64 e = cand[(size_t)tok * 256 + t];
    u64 v = e;
#pragma unroll
    for (int msk = 1; msk < 64; msk <<= 1) {
        u64 o = __shfl_xor(v, msk, 64);
        if (o < v) v = o;
    }
    if (lane == 0) redu[w] = v;
    __syncthreads();
    u64 m01 = redu[0] < redu[1] ? redu[0] : redu[1];
    u64 m23 = redu[2] < redu[3] ? redu[2] : redu[3];
    u64 mall = m01 < m23 ? m01 : m23;
    float dmin = keyinv((unsigned)(mall >> 32));
    float myd = keyinv((unsigned)(e >> 32));
    if (myd <= dmin + DELTA) {
        int p = atomicAdd(&s_cnt, 1);
        if (p < 64) clist[p] = (int)(unsigned)(e & 0xffffffffu);
    }
    __syncthreads();
    int nc = min(s_cnt, 64);

    const float* xrow = inputs + (size_t)tok * DIM;
    float xr[16];
#pragma unroll
    for (int k = 0; k < 16; k++) xr[k] = xrow[t + 256 * k];

    float best = 3.4e38f;
    int bcol = 0x7fffffff;
    for (int i = 0; i < nc; i++) {
        int c = clist[i];
        const float* erow = embedding + (size_t)c * DIM;
        float p = 0.f;
#pragma unroll
        for (int k = 0; k < 16; k++) p += xr[k] * erow[t + 256 * k];
#pragma unroll
        for (int msk = 1; msk < 64; msk <<= 1) p += __shfl_xor(p, msk, 64);
        if (lane == 0) redf[w] = p;
        __syncthreads();
        float dot = (redf[0] + redf[1]) + (redf[2] + redf[3]);
        float dist = enorms[c] - 2.0f * dot;
        __syncthreads();
        if (dist < best || (dist == best && c < bcol)) { best = dist; bcol = c; }
    }
    // all threads agree on bcol (identical reduced values)
    const float* eb = embedding + (size_t)bcol * DIM;
    float* qrow = o_quant + (size_t)tok * DIM;
    float ls = 0.f;
#pragma unroll
    for (int k = 0; k < 16; k++) {
        int d = t + 256 * k;
        float q = eb[d];
        qrow[d] = q;
        float df = q - xr[k];
        ls += df * df;
    }
#pragma unroll
    for (int msk = 1; msk < 64; msk <<= 1) ls += __shfl_xor(ls, msk, 64);
    if (lane == 0) redf[w] = ls;
    __syncthreads();
    if (t == 0) {
        partials[tok] = (redf[0] + redf[1]) + (redf[2] + redf[3]);
        o_idx[tok] = (float)bcol;
        atomicAdd(&counts[bcol], 1);
    }
}

// ---------------------------------------------------------------------------
__global__ __launch_bounds__(1024) void k_cs(const int* __restrict__ counts,
                                             const float* __restrict__ ema_cs,
                                             float* __restrict__ o_ncs,
                                             float* __restrict__ o_perp) {
    __shared__ float red[1024];
    int t = threadIdx.x;
    float pre[8];
    float psum = 0.f, esum = 0.f;
#pragma unroll
    for (int k = 0; k < 8; k++) {
        int j = t * 8 + k;
        float c = (float)counts[j];
        float p = ema_cs[j] * 0.99f + 0.01f * c;
        pre[k] = p;
        psum += p;
        float ap = c * (1.0f / 8192.0f);
        esum += ap * logf(ap + 1e-10f);
    }
    red[t] = psum;
    __syncthreads();
    for (int off = 512; off > 0; off >>= 1) {
        if (t < off) red[t] += red[t + off];
        __syncthreads();
    }
    float n = red[0];
    __syncthreads();
    red[t] = esum;
    __syncthreads();
    for (int off = 512; off > 0; off >>= 1) {
        if (t < off) red[t] += red[t + off];
        __syncthreads();
    }
    if (t == 0) o_perp[0] = expf(-red[0]);
    float scale = n / (n + (float)VOCAB * 1e-5f);
#pragma unroll
    for (int k = 0; k < 8; k++) {
        int j = t * 8 + k;
        o_ncs[j] = (pre[k] + 1e-5f) * scale;
    }
}

// ---------------------------------------------------------------------------
__global__ __launch_bounds__(1024) void k_loss(const float* __restrict__ partials,
                                               float* __restrict__ o_loss) {
    __shared__ float red[1024];
    int t = threadIdx.x;
    float s = 0.f;
#pragma unroll
    for (int k = 0; k < 8; k++) s += partials[t * 8 + k];
    red[t] = s;
    __syncthreads();
    for (int off = 512; off > 0; off >>= 1) {
        if (t < off) red[t] += red[t + off];
        __syncthreads();
    }
    if (t == 0) o_loss[0] = 0.25f * red[0] / ((float)N_TOK * (float)DIM);
}

// ---------------------------------------------------------------------------
// K_ema: block j owns code j; ordered token list (deterministic) then EMA math.
__global__ __launch_bounds__(256) void k_ema(const float* __restrict__ o_idx,
                                             const float* __restrict__ inputs,
                                             const float* __restrict__ ema_w,
                                             const float* __restrict__ o_ncs,
                                             float* __restrict__ o_neww,
                                             float* __restrict__ o_newemb) {
    int j = blockIdx.x, t = threadIdx.x;
    __shared__ int scan[256];
    __shared__ int list[256];
    __shared__ int s_total;
    int c = 0;
    for (int k = 0; k < 32; k++) {
        int tok = t * 32 + k;
        if ((int)o_idx[tok] == j) c++;
    }
    scan[t] = c;
    __syncthreads();
    for (int off = 1; off < 256; off <<= 1) {
        int add = (t >= off) ? scan[t - off] : 0;
        __syncthreads();
        scan[t] += add;
        __syncthreads();
    }
    int excl = scan[t] - c;
    if (t == 255) s_total = scan[255];
    __syncthreads();
    int pos = excl;
    for (int k = 0; k < 32; k++) {
        int tok = t * 32 + k;
        if ((int)o_idx[tok] == j && pos < 256) list[pos++] = tok;
    }
    __syncthreads();
    int total = s_total;
    float nc = o_ncs[j];
    size_t rowoff = (size_t)j * DIM;
#pragma unroll
    for (int k = 0; k < 16; k++) {
        int d = t + 256 * k;
        float s = 0.f;
        for (int q = 0; q < total; q++) s += inputs[(size_t)list[q] * DIM + d];
        float w = ema_w[rowoff + d] * 0.99f + 0.01f * s;
        o_neww[rowoff + d] = w;
        o_newemb[rowoff + d] = w / nc;
    }
}

// ---------------------------------------------------------------------------
extern "C" void kernel_launch(void* const* d_in, const int* in_sizes, int n_in,
                              void* d_out, int out_size, void* d_ws, size_t ws_size,
                              hipStream_t stream) {
    const float* inputs    = (const float*)d_in[0];
    const float* embedding = (const float*)d_in[1];
    const float* ema_w     = (const float*)d_in[2];
    const float* ema_cs    = (const float*)d_in[3];

    float* out = (float*)d_out;
    char* base = (char*)d_out;

    // scratch carved from d_out (lifetime-checked):
    // apk/bpk (fp8, 32MB each) dead after k_gemm; cand/enorms/counts/partials
    // parked inside o_neww region (written only by k_ema, last kernel).
    char* apk       = base;                            // [0, 32M)
    char* bpk       = base + 33554432;                 // [32M, 64M)
    u64* cand       = (u64*)(base + 167772160);        // 16 MB, dead after k_cand
    float* enorms   = (float*)(base + 184549376);      // 32 KB, dead after k_cand
    int* counts     = (int*)(base + 184582144);        // 32 KB, dead after k_cs
    float* partials = (float*)(base + 184614912);      // 32 KB, dead after k_loss

    // output regions (element offsets, return order)
    float* o_loss   = out;                 // [1]
    float* o_quant  = out + 1;             // [8192*4096]
    float* o_perp   = out + 33554433;      // [1]
    float* o_idx    = out + 33554434;      // [8192]
    float* o_ncs    = out + 33562626;      // [8192]
    float* o_neww   = out + 33570818;      // [8192*4096]
    float* o_newemb = out + 67125250;      // [8192*4096]

    k_pack<<<dim3(N_TOK + VOCAB), dim3(256), 0, stream>>>(inputs, embedding, apk, bpk,
                                                          enorms, counts);
    k_gemm<<<dim3(4096), dim3(256), 0, stream>>>(apk, bpk, enorms, cand);
    k_cand<<<dim3(N_TOK), dim3(256), 0, stream>>>(cand, enorms, inputs, embedding,
                                                  o_idx, o_quant, partials, counts);
    k_cs<<<dim3(1), dim3(1024), 0, stream>>>(counts, ema_cs, o_ncs, o_perp);
    k_loss<<<dim3(1), dim3(1024), 0, stream>>>(partials, o_loss);
    k_ema<<<dim3(VOCAB), dim3(256), 0, stream>>>(o_idx, inputs, ema_w, o_ncs, o_neww, o_newemb);
}

// Round 7
// 1803.076 us; speedup vs baseline: 1.1965x; 1.0286x over previous
//
#include <hip/hip_runtime.h>
#include <hip/hip_fp16.h>
#include <stdint.h>

typedef _Float16 f16;
typedef float f32x4 __attribute__((ext_vector_type(4)));
typedef unsigned long long u64;
typedef long long i64;
typedef long long i64x2 __attribute__((ext_vector_type(2)));

#define N_TOK 8192
#define VOCAB 8192
#define DIM   4096
#define DELTA 64.0f

// ---------------------------------------------------------------------------
__device__ __forceinline__ void gload16(const void* g, void* l) {
    __builtin_amdgcn_global_load_lds(
        (const __attribute__((address_space(1))) unsigned int*)(uintptr_t)g,
        (__attribute__((address_space(3))) unsigned int*)(uintptr_t)l,
        16, 0, 0);
}

__device__ __forceinline__ float keyinv(unsigned k) {
    unsigned b = (k & 0x80000000u) ? (k ^ 0x80000000u) : ~k;
    return __uint_as_float(b);
}

__device__ __forceinline__ void ins2(u64& k1, u64& k2, u64 v) {
    if (v < k1) { k2 = k1; k1 = v; }
    else if (v < k2) { k2 = v; }
}

// ---------------------------------------------------------------------------
// K_pack: fp8-e4m3 plane of inputs/embedding with 8B-slot transpose inside
// each 128B K-segment (q8 = g*4 + kk, canonical s8 = kk*4 + g), so k_gemm's
// fragment reads are aligned ds_read_b128 (R5-proven conflict-free pattern).
// Also: embedding norms (f64 acc); zero counts.
__global__ __launch_bounds__(256) void k_pack(const float* __restrict__ inputs,
                                              const float* __restrict__ embedding,
                                              char* __restrict__ apk, char* __restrict__ bpk,
                                              float* __restrict__ enorms,
                                              int* __restrict__ counts) {
    int b = blockIdx.x, t = threadIdx.x;
    bool isB = b >= N_TOK;
    int row = isB ? b - N_TOK : b;
    const float* src = (isB ? embedding : inputs) + (size_t)row * DIM;
    char* dst = (isB ? bpk : apk) + (size_t)row * DIM;
    double nrm = 0.0;
#pragma unroll
    for (int k = 0; k < 4; k++) {
        int d0 = t * 4 + 1024 * k;
        float4 v = *(const float4*)(src + d0);
        nrm += (double)v.x * v.x + (double)v.y * v.y
             + (double)v.z * v.z + (double)v.w * v.w;
        int packed = 0;
        packed = __builtin_amdgcn_cvt_pk_fp8_f32(v.x, v.y, packed, false);
        packed = __builtin_amdgcn_cvt_pk_fp8_f32(v.z, v.w, packed, true);
        // 8B-slot transpose within the 128B K-segment
        int c = d0 & 127;
        int s8 = c >> 3, kk = s8 >> 2, g = s8 & 3;
        int c2 = ((g * 4 + kk) << 3) | (c & 7);
        *(int*)(dst + (d0 & ~127) + c2) = packed;
    }
    if (isB) {
        __shared__ double red[256];
        red[t] = nrm;
        __syncthreads();
        for (int off = 128; off > 0; off >>= 1) {
            if (t < off) red[t] += red[t + off];
            __syncthreads();
        }
        if (t == 0) {
            enorms[row] = (float)red[0];
            counts[row] = 0;
        }
    }
}

// ---------------------------------------------------------------------------
// K_gemm: approx S = x·e via fp8-e4m3 MFMA (16x16x32_fp8_fp8). m97 structure:
// 128x128 tile, BK=128 fp8 (32KB single-buffer LDS), 4 waves,
// stage->sync->compute->sync; ~3-4 blocks/CU hide the barrier drain.
// Fragment reads are b128 (two K-slices per read via pack-time slot
// transpose) with the R5-proven 16B-granule XOR swizzle -> 0 bank conflicts.
// Epilogue: top-2 (key|col) per (row, 64-col slice); exact recheck downstream.
__global__ __launch_bounds__(256) void k_gemm(const char* __restrict__ apk,
                                              const char* __restrict__ bpk,
                                              const float* __restrict__ enorms,
                                              u64* __restrict__ cand) {
    __shared__ alignas(16) char lds[32768];   // A 16KB | B 16KB
    int wg = blockIdx.x;
    wg = (wg & 7) * 512 + (wg >> 3);          // XCD swizzle (4096 % 8 == 0)
    int bm = wg >> 6, bn = wg & 63;
    int tid = threadIdx.x;
    int lane = tid & 63, wid = tid >> 6;
    int wm = wid >> 1, wn = wid & 1;

    // staging: 8 issues/thread/K-step (4 A + 4 B); source pre-swizzled at 16B
    const char* srcs[8];
    unsigned lof[8];
#pragma unroll
    for (int e = 0; e < 8; e++) {
        int tile = e >> 2, q = e & 3;
        int s = q * 256 + tid;                 // 16B slot 0..1023 within tile
        int r = s >> 3;                        // row 0..127 (128B rows)
        int c16 = (s & 7) ^ (r & 7);           // inverse swizzle on source
        int row = (tile ? bn : bm) * 128 + r;
        srcs[e] = (tile ? bpk : apk) + (size_t)row * DIM + c16 * 16;
        lof[e] = tile * 16384 + q * 4096 + wid * 1024;   // + lane*16 by HW
    }

    f32x4 acc[4][4];
#pragma unroll
    for (int m = 0; m < 4; m++)
#pragma unroll
        for (int n = 0; n < 4; n++) acc[m][n] = (f32x4){0.f, 0.f, 0.f, 0.f};

    const int g2 = (lane >> 4) << 1;          // 2*g: lane's unit base
    const int ra = wm * 64 + (lane & 15);     // A row base (+ m*16)
    const int rb = wn * 64 + (lane & 15);     // B row base (+ n*16)

    for (int kt = 0; kt < 32; ++kt) {
#pragma unroll
        for (int e = 0; e < 8; e++) { gload16(srcs[e], &lds[lof[e]]); srcs[e] += 128; }
        __syncthreads();   // drains vmcnt -> tiles ready
#pragma unroll
        for (int h = 0; h < 2; h++) {
            i64x2 av[4], bv[4];
#pragma unroll
            for (int m = 0; m < 4; m++) {
                int r = ra + m * 16;
                av[m] = *(const i64x2*)&lds[r * 128 + (((g2 + h) ^ (r & 7)) << 4)];
            }
#pragma unroll
            for (int n = 0; n < 4; n++) {
                int r = rb + n * 16;
                bv[n] = *(const i64x2*)&lds[16384 + r * 128 + (((g2 + h) ^ (r & 7)) << 4)];
            }
#pragma unroll
            for (int m = 0; m < 4; m++)
#pragma unroll
                for (int n = 0; n < 4; n++) {
                    acc[m][n] = __builtin_amdgcn_mfma_f32_16x16x32_fp8_fp8(av[m][0], bv[n][0], acc[m][n], 0, 0, 0);
                    acc[m][n] = __builtin_amdgcn_mfma_f32_16x16x32_fp8_fp8(av[m][1], bv[n][1], acc[m][n], 0, 0, 0);
                }
        }
        __syncthreads();   // readers done before next stage overwrites
    }

    // epilogue: approx dist = ||e||^2 - 2S; keep 2 smallest per (row, 64-col slice)
    float en[4];
    int colb = bn * 128 + wn * 64 + (lane & 15);
#pragma unroll
    for (int n = 0; n < 4; n++) en[n] = enorms[colb + n * 16];
#pragma unroll
    for (int m = 0; m < 4; m++) {
#pragma unroll
        for (int reg = 0; reg < 4; reg++) {
            u64 k1 = ~0ull, k2 = ~0ull;
#pragma unroll
            for (int n = 0; n < 4; n++) {
                float d = en[n] - 2.0f * acc[m][n][reg];
                unsigned b = __float_as_uint(d);
                unsigned key = (b & 0x80000000u) ? ~b : (b | 0x80000000u);
                ins2(k1, k2, ((u64)key << 32) | (unsigned)(colb + n * 16));
            }
#pragma unroll
            for (int msk = 1; msk < 16; msk <<= 1) {
                u64 o1 = __shfl_xor(k1, msk, 64);
                u64 o2 = __shfl_xor(k2, msk, 64);
                ins2(k1, k2, o1);
                ins2(k1, k2, o2);
            }
            if ((lane & 15) == 0) {
                int rowg = bm * 128 + wm * 64 + m * 16 + ((lane >> 4) << 2) + reg;
                size_t slot = ((size_t)rowg * 64 + bn) * 2 + wn;
                ulonglong2 v; v.x = k1; v.y = k2;
                *(ulonglong2*)&cand[slot * 2] = v;
            }
        }
    }
}

// ---------------------------------------------------------------------------
// K_cand: per token, min over 256 stored entries; collect candidates within
// DELTA; exact f32 recheck; fused quantize-copy + loss partial + count.
__global__ __launch_bounds__(256) void k_cand(const u64* __restrict__ cand,
                                              const float* __restrict__ enorms,
                                              const float* __restrict__ inputs,
                                              const float* __restrict__ embedding,
                                              float* __restrict__ o_idx,
                                              float* __restrict__ o_quant,
                                              float* __restrict__ partials,
                                              int* __restrict__ counts) {
    int tok = blockIdx.x, t = threadIdx.x;
    int lane = t & 63, w = t >> 6;
    __shared__ u64 redu[4];
    __shared__ float redf[4];
    __shared__ int clist[64];
    __shared__ int s_cnt;
    if (t == 0) s_cnt = 0;
    u64 e = cand[(size_t)tok * 256 + t];
    u64 v = e;
#pragma unroll
    for (int msk = 1; msk < 64; msk <<= 1) {
        u64 o = __shfl_xor(v, msk, 64);
        if (o < v) v = o;
    }
    if (lane == 0) redu[w] = v;
    __syncthreads();
    u64 m01 = redu[0] < redu[1] ? redu[0] : redu[1];
    u64 m23 = redu[2] < redu[3] ? redu[2] : redu[3];
    u64 mall = m01 < m23 ? m01 : m23;
    float dmin = keyinv((unsigned)(mall >> 32));
    float myd = keyinv((unsigned)(e >> 32));
    if (myd <= dmin + DELTA) {
        int p = atomicAdd(&s_cnt, 1);
        if (p < 64) clist[p] = (int)(unsigned)(e & 0xffffffffu);
    }
    __syncthreads();
    int nc = min(s_cnt, 64);

    const float* xrow = inputs + (size_t)tok * DIM;
    float xr[16];
#pragma unroll
    for (int k = 0; k < 16; k++) xr[k] = xrow[t + 256 * k];

    float best = 3.4e38f;
    int bcol = 0x7fffffff;
    for (int i = 0; i < nc; i++) {
        int c = clist[i];
        const float* erow = embedding + (size_t)c * DIM;
        float p = 0.f;
#pragma unroll
        for (int k = 0; k < 16; k++) p += xr[k] * erow[t + 256 * k];
#pragma unroll
        for (int msk = 1; msk < 64; msk <<= 1) p += __shfl_xor(p, msk, 64);
        if (lane == 0) redf[w] = p;
        __syncthreads();
        float dot = (redf[0] + redf[1]) + (redf[2] + redf[3]);
        float dist = enorms[c] - 2.0f * dot;
        __syncthreads();
        if (dist < best || (dist == best && c < bcol)) { best = dist; bcol = c; }
    }
    // all threads agree on bcol (identical reduced values)
    const float* eb = embedding + (size_t)bcol * DIM;
    float* qrow = o_quant + (size_t)tok * DIM;
    float ls = 0.f;
#pragma unroll
    for (int k = 0; k < 16; k++) {
        int d = t + 256 * k;
        float q = eb[d];
        qrow[d] = q;
        float df = q - xr[k];
        ls += df * df;
    }
#pragma unroll
    for (int msk = 1; msk < 64; msk <<= 1) ls += __shfl_xor(ls, msk, 64);
    if (lane == 0) redf[w] = ls;
    __syncthreads();
    if (t == 0) {
        partials[tok] = (redf[0] + redf[1]) + (redf[2] + redf[3]);
        o_idx[tok] = (float)bcol;
        atomicAdd(&counts[bcol], 1);
    }
}

// ---------------------------------------------------------------------------
__global__ __launch_bounds__(1024) void k_cs(const int* __restrict__ counts,
                                             const float* __restrict__ ema_cs,
                                             float* __restrict__ o_ncs,
                                             float* __restrict__ o_perp) {
    __shared__ float red[1024];
    int t = threadIdx.x;
    float pre[8];
    float psum = 0.f, esum = 0.f;
#pragma unroll
    for (int k = 0; k < 8; k++) {
        int j = t * 8 + k;
        float c = (float)counts[j];
        float p = ema_cs[j] * 0.99f + 0.01f * c;
        pre[k] = p;
        psum += p;
        float ap = c * (1.0f / 8192.0f);
        esum += ap * logf(ap + 1e-10f);
    }
    red[t] = psum;
    __syncthreads();
    for (int off = 512; off > 0; off >>= 1) {
        if (t < off) red[t] += red[t + off];
        __syncthreads();
    }
    float n = red[0];
    __syncthreads();
    red[t] = esum;
    __syncthreads();
    for (int off = 512; off > 0; off >>= 1) {
        if (t < off) red[t] += red[t + off];
        __syncthreads();
    }
    if (t == 0) o_perp[0] = expf(-red[0]);
    float scale = n / (n + (float)VOCAB * 1e-5f);
#pragma unroll
    for (int k = 0; k < 8; k++) {
        int j = t * 8 + k;
        o_ncs[j] = (pre[k] + 1e-5f) * scale;
    }
}

// ---------------------------------------------------------------------------
__global__ __launch_bounds__(1024) void k_loss(const float* __restrict__ partials,
                                               float* __restrict__ o_loss) {
    __shared__ float red[1024];
    int t = threadIdx.x;
    float s = 0.f;
#pragma unroll
    for (int k = 0; k < 8; k++) s += partials[t * 8 + k];
    red[t] = s;
    __syncthreads();
    for (int off = 512; off > 0; off >>= 1) {
        if (t < off) red[t] += red[t + off];
        __syncthreads();
    }
    if (t == 0) o_loss[0] = 0.25f * red[0] / ((float)N_TOK * (float)DIM);
}

// ---------------------------------------------------------------------------
// K_ema: block j owns code j; ordered token list (deterministic) then EMA math.
__global__ __launch_bounds__(256) void k_ema(const float* __restrict__ o_idx,
                                             const float* __restrict__ inputs,
                                             const float* __restrict__ ema_w,
                                             const float* __restrict__ o_ncs,
                                             float* __restrict__ o_neww,
                                             float* __restrict__ o_newemb) {
    int j = blockIdx.x, t = threadIdx.x;
    __shared__ int scan[256];
    __shared__ int list[256];
    __shared__ int s_total;
    int c = 0;
    for (int k = 0; k < 32; k++) {
        int tok = t * 32 + k;
        if ((int)o_idx[tok] == j) c++;
    }
    scan[t] = c;
    __syncthreads();
    for (int off = 1; off < 256; off <<= 1) {
        int add = (t >= off) ? scan[t - off] : 0;
        __syncthreads();
        scan[t] += add;
        __syncthreads();
    }
    int excl = scan[t] - c;
    if (t == 255) s_total = scan[255];
    __syncthreads();
    int pos = excl;
    for (int k = 0; k < 32; k++) {
        int tok = t * 32 + k;
        if ((int)o_idx[tok] == j && pos < 256) list[pos++] = tok;
    }
    __syncthreads();
    int total = s_total;
    float nc = o_ncs[j];
    size_t rowoff = (size_t)j * DIM;
#pragma unroll
    for (int k = 0; k < 16; k++) {
        int d = t + 256 * k;
        float s = 0.f;
        for (int q = 0; q < total; q++) s += inputs[(size_t)list[q] * DIM + d];
        float w = ema_w[rowoff + d] * 0.99f + 0.01f * s;
        o_neww[rowoff + d] = w;
        o_newemb[rowoff + d] = w / nc;
    }
}

// ---------------------------------------------------------------------------
extern "C" void kernel_launch(void* const* d_in, const int* in_sizes, int n_in,
                              void* d_out, int out_size, void* d_ws, size_t ws_size,
                              hipStream_t stream) {
    const float* inputs    = (const float*)d_in[0];
    const float* embedding = (const float*)d_in[1];
    const float* ema_w     = (const float*)d_in[2];
    const float* ema_cs    = (const float*)d_in[3];

    float* out = (float*)d_out;
    char* base = (char*)d_out;

    // scratch carved from d_out (lifetime-checked):
    // apk/bpk (fp8, 32MB each) dead after k_gemm; cand/enorms/counts/partials
    // parked inside o_neww region (written only by k_ema, last kernel).
    char* apk       = base;                            // [0, 32M)
    char* bpk       = base + 33554432;                 // [32M, 64M)
    u64* cand       = (u64*)(base + 167772160);        // 16 MB, dead after k_cand
    float* enorms   = (float*)(base + 184549376);      // 32 KB, dead after k_cand
    int* counts     = (int*)(base + 184582144);        // 32 KB, dead after k_cs
    float* partials = (float*)(base + 184614912);      // 32 KB, dead after k_loss

    // output regions (element offsets, return order)
    float* o_loss   = out;                 // [1]
    float* o_quant  = out + 1;             // [8192*4096]
    float* o_perp   = out + 33554433;      // [1]
    float* o_idx    = out + 33554434;      // [8192]
    float* o_ncs    = out + 33562626;      // [8192]
    float* o_neww   = out + 33570818;      // [8192*4096]
    float* o_newemb = out + 67125250;      // [8192*4096]

    k_pack<<<dim3(N_TOK + VOCAB), dim3(256), 0, stream>>>(inputs, embedding, apk, bpk,
                                                          enorms, counts);
    k_gemm<<<dim3(4096), dim3(256), 0, stream>>>(apk, bpk, enorms, cand);
    k_cand<<<dim3(N_TOK), dim3(256), 0, stream>>>(cand, enorms, inputs, embedding,
                                                  o_idx, o_quant, partials, counts);
    k_cs<<<dim3(1), dim3(1024), 0, stream>>>(counts, ema_cs, o_ncs, o_perp);
    k_loss<<<dim3(1), dim3(1024), 0, stream>>>(partials, o_loss);
    k_ema<<<dim3(VOCAB), dim3(256), 0, stream>>>(o_idx, inputs, ema_w, o_ncs, o_neww, o_newemb);
}

// Round 8
// 1700.104 us; speedup vs baseline: 1.2689x; 1.0606x over previous
//
#include <hip/hip_runtime.h>
#include <hip/hip_fp16.h>
#include <stdint.h>

typedef _Float16 f16;
typedef float f32x4 __attribute__((ext_vector_type(4)));
typedef unsigned long long u64;
typedef long long i64;
typedef long long i64x2 __attribute__((ext_vector_type(2)));

#define N_TOK 8192
#define VOCAB 8192
#define DIM   4096
#define DELTA 64.0f

// ---------------------------------------------------------------------------
__device__ __forceinline__ void gload16(const void* g, void* l) {
    __builtin_amdgcn_global_load_lds(
        (const __attribute__((address_space(1))) unsigned int*)(uintptr_t)g,
        (__attribute__((address_space(3))) unsigned int*)(uintptr_t)l,
        16, 0, 0);
}

__device__ __forceinline__ float keyinv(unsigned k) {
    unsigned b = (k & 0x80000000u) ? (k ^ 0x80000000u) : ~k;
    return __uint_as_float(b);
}

__device__ __forceinline__ void ins2(u64& k1, u64& k2, u64 v) {
    if (v < k1) { k2 = k1; k1 = v; }
    else if (v < k2) { k2 = v; }
}

// ---------------------------------------------------------------------------
// K_pack: fp8-e4m3 plane with 8B-slot permutation inside each 128B K-segment:
// q8 = ((kk>>1)<<3)|(g<<1)|(kk&1)  (canonical s8 = kk*4+g), so that k_gemm's
// phase-h, lane-group-g b128 read sits at 16B-unit (4h+g) — replicating the
// f16 rounds' verified-0-conflict read pattern. Also enorms (f64 acc), counts=0.
__global__ __launch_bounds__(256) void k_pack(const float* __restrict__ inputs,
                                              const float* __restrict__ embedding,
                                              char* __restrict__ apk, char* __restrict__ bpk,
                                              float* __restrict__ enorms,
                                              int* __restrict__ counts) {
    int b = blockIdx.x, t = threadIdx.x;
    bool isB = b >= N_TOK;
    int row = isB ? b - N_TOK : b;
    const float* src = (isB ? embedding : inputs) + (size_t)row * DIM;
    char* dst = (isB ? bpk : apk) + (size_t)row * DIM;
    double nrm = 0.0;
#pragma unroll
    for (int k = 0; k < 4; k++) {
        int d0 = t * 4 + 1024 * k;
        float4 v = *(const float4*)(src + d0);
        nrm += (double)v.x * v.x + (double)v.y * v.y
             + (double)v.z * v.z + (double)v.w * v.w;
        int packed = 0;
        packed = __builtin_amdgcn_cvt_pk_fp8_f32(v.x, v.y, packed, false);
        packed = __builtin_amdgcn_cvt_pk_fp8_f32(v.z, v.w, packed, true);
        int c = d0 & 127;
        int s8 = c >> 3, kk = s8 >> 2, g = s8 & 3;
        int q8 = ((kk & 2) << 2) | (g << 1) | (kk & 1);
        *(int*)(dst + (d0 & ~127) + (q8 << 3) + (c & 7)) = packed;
    }
    if (isB) {
        __shared__ double red[256];
        red[t] = nrm;
        __syncthreads();
        for (int off = 128; off > 0; off >>= 1) {
            if (t < off) red[t] += red[t + off];
            __syncthreads();
        }
        if (t == 0) {
            enorms[row] = (float)red[0];
            counts[row] = 0;
        }
    }
}

// ---------------------------------------------------------------------------
// K_gemm: approx S = x·e via fp8-e4m3 MFMA. 128x128 tile, BK=128 fp8,
// 4 waves, DOUBLE-buffered 2x32KB LDS with counted-vmcnt pipeline (T4):
// per iter: issue next tile's 8 gloads -> s_waitcnt vmcnt(8) (own-wave) ->
// raw s_barrier -> setprio(1) MFMA cluster setprio(0) -> raw s_barrier.
// Loads stay in flight across the whole compute phase (never drain to 0
// mid-loop). Fragment reads use the f16-verified unit pattern (4h+g)^(r&7).
// Epilogue: top-2 (key|col) per (row, 64-col slice); exact recheck downstream.
__global__ __launch_bounds__(256) void k_gemm(const char* __restrict__ apk,
                                              const char* __restrict__ bpk,
                                              const float* __restrict__ enorms,
                                              u64* __restrict__ cand) {
    __shared__ alignas(16) char lds[65536];   // 2 x (A 16KB | B 16KB)
    int wg = blockIdx.x;
    wg = (wg & 7) * 512 + (wg >> 3);          // XCD swizzle (4096 % 8 == 0)
    int bm = wg >> 6, bn = wg & 63;
    int tid = threadIdx.x;
    int lane = tid & 63, wid = tid >> 6;
    int wm = wid >> 1, wn = wid & 1;

    // staging: 8 issues/thread/K-tile (4 A + 4 B); source pre-swizzled at 16B
    const char* srcs[8];
    unsigned lof[8];
#pragma unroll
    for (int e = 0; e < 8; e++) {
        int tile = e >> 2, q = e & 3;
        int s = q * 256 + tid;                 // 16B slot 0..1023 within tile
        int r = s >> 3;                        // row 0..127 (128B rows)
        int c16 = (s & 7) ^ (r & 7);           // inverse swizzle on source
        int row = (tile ? bn : bm) * 128 + r;
        srcs[e] = (tile ? bpk : apk) + (size_t)row * DIM + c16 * 16;
        lof[e] = tile * 16384 + q * 4096 + wid * 1024;   // + lane*16 by HW
    }

    f32x4 acc[4][4];
#pragma unroll
    for (int m = 0; m < 4; m++)
#pragma unroll
        for (int n = 0; n < 4; n++) acc[m][n] = (f32x4){0.f, 0.f, 0.f, 0.f};

    const int g = lane >> 4;                  // lane group 0..3
    const int ra = wm * 64 + (lane & 15);     // A row base (+ m*16)
    const int rb = wn * 64 + (lane & 15);     // B row base (+ n*16)

#define STAGE(buf) { _Pragma("unroll") for (int e = 0; e < 8; e++) { \
        gload16(srcs[e], &lds[(buf) * 32768u + lof[e]]); srcs[e] += 128; } }

    STAGE(0);   // prologue: tile 0 -> buf 0 (8 loads in flight)

    for (int kt = 0; kt < 32; ++kt) {
        const unsigned cur = (kt & 1) ? 32768u : 0u;
        if (kt < 31) {
            STAGE((kt & 1) ^ 1);   // next tile: 8 more in flight (16 total)
            asm volatile("s_waitcnt vmcnt(8)" ::: "memory");   // current tile landed
        } else {
            asm volatile("s_waitcnt vmcnt(0)" ::: "memory");
        }
        __builtin_amdgcn_sched_barrier(0);
        __builtin_amdgcn_s_barrier();          // all waves' current-tile loads landed
        __builtin_amdgcn_s_setprio(1);
#pragma unroll
        for (int h = 0; h < 2; h++) {
            i64x2 av[4], bv[4];
#pragma unroll
            for (int m = 0; m < 4; m++) {
                int r = ra + m * 16;
                av[m] = *(const i64x2*)&lds[cur + r * 128 + ((((h << 2) + g) ^ (r & 7)) << 4)];
            }
#pragma unroll
            for (int n = 0; n < 4; n++) {
                int r = rb + n * 16;
                bv[n] = *(const i64x2*)&lds[cur + 16384 + r * 128 + ((((h << 2) + g) ^ (r & 7)) << 4)];
            }
#pragma unroll
            for (int m = 0; m < 4; m++)
#pragma unroll
                for (int n = 0; n < 4; n++) {
                    acc[m][n] = __builtin_amdgcn_mfma_f32_16x16x32_fp8_fp8(av[m][0], bv[n][0], acc[m][n], 0, 0, 0);
                    acc[m][n] = __builtin_amdgcn_mfma_f32_16x16x32_fp8_fp8(av[m][1], bv[n][1], acc[m][n], 0, 0, 0);
                }
        }
        __builtin_amdgcn_s_setprio(0);
        __builtin_amdgcn_s_barrier();          // readers done before next STAGE overwrites
    }
#undef STAGE

    // epilogue: approx dist = ||e||^2 - 2S; keep 2 smallest per (row, 64-col slice)
    float en[4];
    int colb = bn * 128 + wn * 64 + (lane & 15);
#pragma unroll
    for (int n = 0; n < 4; n++) en[n] = enorms[colb + n * 16];
#pragma unroll
    for (int m = 0; m < 4; m++) {
#pragma unroll
        for (int reg = 0; reg < 4; reg++) {
            u64 k1 = ~0ull, k2 = ~0ull;
#pragma unroll
            for (int n = 0; n < 4; n++) {
                float d = en[n] - 2.0f * acc[m][n][reg];
                unsigned b = __float_as_uint(d);
                unsigned key = (b & 0x80000000u) ? ~b : (b | 0x80000000u);
                ins2(k1, k2, ((u64)key << 32) | (unsigned)(colb + n * 16));
            }
#pragma unroll
            for (int msk = 1; msk < 16; msk <<= 1) {
                u64 o1 = __shfl_xor(k1, msk, 64);
                u64 o2 = __shfl_xor(k2, msk, 64);
                ins2(k1, k2, o1);
                ins2(k1, k2, o2);
            }
            if ((lane & 15) == 0) {
                int rowg = bm * 128 + wm * 64 + m * 16 + ((lane >> 4) << 2) + reg;
                size_t slot = ((size_t)rowg * 64 + bn) * 2 + wn;
                ulonglong2 v; v.x = k1; v.y = k2;
                *(ulonglong2*)&cand[slot * 2] = v;
            }
        }
    }
}

// ---------------------------------------------------------------------------
// K_cand: per token, min over 256 stored entries; collect candidates within
// DELTA; exact f32 recheck; fused quantize-copy + loss partial + count.
__global__ __launch_bounds__(256) void k_cand(const u64* __restrict__ cand,
                                              const float* __restrict__ enorms,
                                              const float* __restrict__ inputs,
                                              const float* __restrict__ embedding,
                                              float* __restrict__ o_idx,
                                              float* __restrict__ o_quant,
                                              float* __restrict__ partials,
                                              int* __restrict__ counts) {
    int tok = blockIdx.x, t = threadIdx.x;
    int lane = t & 63, w = t >> 6;
    __shared__ u64 redu[4];
    __shared__ float redf[4];
    __shared__ int clist[64];
    __shared__ int s_cnt;
    if (t == 0) s_cnt = 0;
    u64 e = cand[(size_t)tok * 256 + t];
    u64 v = e;
#pragma unroll
    for (int msk = 1; msk < 64; msk <<= 1) {
        u64 o = __shfl_xor(v, msk, 64);
        if (o < v) v = o;
    }
    if (lane == 0) redu[w] = v;
    __syncthreads();
    u64 m01 = redu[0] < redu[1] ? redu[0] : redu[1];
    u64 m23 = redu[2] < redu[3] ? redu[2] : redu[3];
    u64 mall = m01 < m23 ? m01 : m23;
    float dmin = keyinv((unsigned)(mall >> 32));
    float myd = keyinv((unsigned)(e >> 32));
    if (myd <= dmin + DELTA) {
        int p = atomicAdd(&s_cnt, 1);
        if (p < 64) clist[p] = (int)(unsigned)(e & 0xffffffffu);
    }
    __syncthreads();
    int nc = min(s_cnt, 64);

    const float* xrow = inputs + (size_t)tok * DIM;
    float xr[16];
#pragma unroll
    for (int k = 0; k < 16; k++) xr[k] = xrow[t + 256 * k];

    float best = 3.4e38f;
    int bcol = 0x7fffffff;
    for (int i = 0; i < nc; i++) {
        int c = clist[i];
        const float* erow = embedding + (size_t)c * DIM;
        float p = 0.f;
#pragma unroll
        for (int k = 0; k < 16; k++) p += xr[k] * erow[t + 256 * k];
#pragma unroll
        for (int msk = 1; msk < 64; msk <<= 1) p += __shfl_xor(p, msk, 64);
        if (lane == 0) redf[w] = p;
        __syncthreads();
        float dot = (redf[0] + redf[1]) + (redf[2] + redf[3]);
        float dist = enorms[c] - 2.0f * dot;
        __syncthreads();
        if (dist < best || (dist == best && c < bcol)) { best = dist; bcol = c; }
    }
    // all threads agree on bcol (identical reduced values)
    const float* eb = embedding + (size_t)bcol * DIM;
    float* qrow = o_quant + (size_t)tok * DIM;
    float ls = 0.f;
#pragma unroll
    for (int k = 0; k < 16; k++) {
        int d = t + 256 * k;
        float q = eb[d];
        qrow[d] = q;
        float df = q - xr[k];
        ls += df * df;
    }
#pragma unroll
    for (int msk = 1; msk < 64; msk <<= 1) ls += __shfl_xor(ls, msk, 64);
    if (lane == 0) redf[w] = ls;
    __syncthreads();
    if (t == 0) {
        partials[tok] = (redf[0] + redf[1]) + (redf[2] + redf[3]);
        o_idx[tok] = (float)bcol;
        atomicAdd(&counts[bcol], 1);
    }
}

// ---------------------------------------------------------------------------
__global__ __launch_bounds__(1024) void k_cs(const int* __restrict__ counts,
                                             const float* __restrict__ ema_cs,
                                             float* __restrict__ o_ncs,
                                             float* __restrict__ o_perp) {
    __shared__ float red[1024];
    int t = threadIdx.x;
    float pre[8];
    float psum = 0.f, esum = 0.f;
#pragma unroll
    for (int k = 0; k < 8; k++) {
        int j = t * 8 + k;
        float c = (float)counts[j];
        float p = ema_cs[j] * 0.99f + 0.01f * c;
        pre[k] = p;
        psum += p;
        float ap = c * (1.0f / 8192.0f);
        esum += ap * logf(ap + 1e-10f);
    }
    red[t] = psum;
    __syncthreads();
    for (int off = 512; off > 0; off >>= 1) {
        if (t < off) red[t] += red[t + off];
        __syncthreads();
    }
    float n = red[0];
    __syncthreads();
    red[t] = esum;
    __syncthreads();
    for (int off = 512; off > 0; off >>= 1) {
        if (t < off) red[t] += red[t + off];
        __syncthreads();
    }
    if (t == 0) o_perp[0] = expf(-red[0]);
    float scale = n / (n + (float)VOCAB * 1e-5f);
#pragma unroll
    for (int k = 0; k < 8; k++) {
        int j = t * 8 + k;
        o_ncs[j] = (pre[k] + 1e-5f) * scale;
    }
}

// ---------------------------------------------------------------------------
__global__ __launch_bounds__(1024) void k_loss(const float* __restrict__ partials,
                                               float* __restrict__ o_loss) {
    __shared__ float red[1024];
    int t = threadIdx.x;
    float s = 0.f;
#pragma unroll
    for (int k = 0; k < 8; k++) s += partials[t * 8 + k];
    red[t] = s;
    __syncthreads();
    for (int off = 512; off > 0; off >>= 1) {
        if (t < off) red[t] += red[t + off];
        __syncthreads();
    }
    if (t == 0) o_loss[0] = 0.25f * red[0] / ((float)N_TOK * (float)DIM);
}

// ---------------------------------------------------------------------------
// K_ema: block j owns code j; ordered token list (deterministic) then EMA math.
__global__ __launch_bounds__(256) void k_ema(const float* __restrict__ o_idx,
                                             const float* __restrict__ inputs,
                                             const float* __restrict__ ema_w,
                                             const float* __restrict__ o_ncs,
                                             float* __restrict__ o_neww,
                                             float* __restrict__ o_newemb) {
    int j = blockIdx.x, t = threadIdx.x;
    __shared__ int scan[256];
    __shared__ int list[256];
    __shared__ int s_total;
    int c = 0;
    for (int k = 0; k < 32; k++) {
        int tok = t * 32 + k;
        if ((int)o_idx[tok] == j) c++;
    }
    scan[t] = c;
    __syncthreads();
    for (int off = 1; off < 256; off <<= 1) {
        int add = (t >= off) ? scan[t - off] : 0;
        __syncthreads();
        scan[t] += add;
        __syncthreads();
    }
    int excl = scan[t] - c;
    if (t == 255) s_total = scan[255];
    __syncthreads();
    int pos = excl;
    for (int k = 0; k < 32; k++) {
        int tok = t * 32 + k;
        if ((int)o_idx[tok] == j && pos < 256) list[pos++] = tok;
    }
    __syncthreads();
    int total = s_total;
    float nc = o_ncs[j];
    size_t rowoff = (size_t)j * DIM;
#pragma unroll
    for (int k = 0; k < 16; k++) {
        int d = t + 256 * k;
        float s = 0.f;
        for (int q = 0; q < total; q++) s += inputs[(size_t)list[q] * DIM + d];
        float w = ema_w[rowoff + d] * 0.99f + 0.01f * s;
        o_neww[rowoff + d] = w;
        o_newemb[rowoff + d] = w / nc;
    }
}

// ---------------------------------------------------------------------------
extern "C" void kernel_launch(void* const* d_in, const int* in_sizes, int n_in,
                              void* d_out, int out_size, void* d_ws, size_t ws_size,
                              hipStream_t stream) {
    const float* inputs    = (const float*)d_in[0];
    const float* embedding = (const float*)d_in[1];
    const float* ema_w     = (const float*)d_in[2];
    const float* ema_cs    = (const float*)d_in[3];

    float* out = (float*)d_out;
    char* base = (char*)d_out;

    // scratch carved from d_out (lifetime-checked):
    // apk/bpk (fp8, 32MB each) dead after k_gemm; cand/enorms/counts/partials
    // parked inside o_neww region (written only by k_ema, last kernel).
    char* apk       = base;                            // [0, 32M)
    char* bpk       = base + 33554432;                 // [32M, 64M)
    u64* cand       = (u64*)(base + 167772160);        // 16 MB, dead after k_cand
    float* enorms   = (float*)(base + 184549376);      // 32 KB, dead after k_cand
    int* counts     = (int*)(base + 184582144);        // 32 KB, dead after k_cs
    float* partials = (float*)(base + 184614912);      // 32 KB, dead after k_loss

    // output regions (element offsets, return order)
    float* o_loss   = out;                 // [1]
    float* o_quant  = out + 1;             // [8192*4096]
    float* o_perp   = out + 33554433;      // [1]
    float* o_idx    = out + 33554434;      // [8192]
    float* o_ncs    = out + 33562626;      // [8192]
    float* o_neww   = out + 33570818;      // [8192*4096]
    float* o_newemb = out + 67125250;      // [8192*4096]

    k_pack<<<dim3(N_TOK + VOCAB), dim3(256), 0, stream>>>(inputs, embedding, apk, bpk,
                                                          enorms, counts);
    k_gemm<<<dim3(4096), dim3(256), 0, stream>>>(apk, bpk, enorms, cand);
    k_cand<<<dim3(N_TOK), dim3(256), 0, stream>>>(cand, enorms, inputs, embedding,
                                                  o_idx, o_quant, partials, counts);
    k_cs<<<dim3(1), dim3(1024), 0, stream>>>(counts, ema_cs, o_ncs, o_perp);
    k_loss<<<dim3(1), dim3(1024), 0, stream>>>(partials, o_loss);
    k_ema<<<dim3(VOCAB), dim3(256), 0, stream>>>(o_idx, inputs, ema_w, o_ncs, o_neww, o_newemb);
}

// Round 9
// 1360.131 us; speedup vs baseline: 1.5861x; 1.2500x over previous
//
#include <hip/hip_runtime.h>
#include <hip/hip_fp16.h>
#include <stdint.h>

typedef _Float16 f16;
typedef float f32x4 __attribute__((ext_vector_type(4)));
typedef unsigned long long u64;
typedef long long i64;
typedef long long i64x2 __attribute__((ext_vector_type(2)));

#define N_TOK 8192
#define VOCAB 8192
#define DIM   4096
#define DELTA 64.0f

// ---------------------------------------------------------------------------
__device__ __forceinline__ void gload16(const void* g, void* l) {
    __builtin_amdgcn_global_load_lds(
        (const __attribute__((address_space(1))) unsigned int*)(uintptr_t)g,
        (__attribute__((address_space(3))) unsigned int*)(uintptr_t)l,
        16, 0, 0);
}

__device__ __forceinline__ float keyinv(unsigned k) {
    unsigned b = (k & 0x80000000u) ? (k ^ 0x80000000u) : ~k;
    return __uint_as_float(b);
}

__device__ __forceinline__ void ins2(u64& k1, u64& k2, u64 v) {
    if (v < k1) { k2 = k1; k1 = v; }
    else if (v < k2) { k2 = v; }
}

// ---------------------------------------------------------------------------
// K_pack: fp8-e4m3 plane with 8B-slot permutation inside each 128B K-segment
// (q8 = ((kk&2)<<2)|(g<<1)|(kk&1)), replicating the f16-verified 0-conflict
// read pattern in k_gemm. Also enorms (f64 acc), counts=0.
__global__ __launch_bounds__(256) void k_pack(const float* __restrict__ inputs,
                                              const float* __restrict__ embedding,
                                              char* __restrict__ apk, char* __restrict__ bpk,
                                              float* __restrict__ enorms,
                                              int* __restrict__ counts) {
    int b = blockIdx.x, t = threadIdx.x;
    bool isB = b >= N_TOK;
    int row = isB ? b - N_TOK : b;
    const float* src = (isB ? embedding : inputs) + (size_t)row * DIM;
    char* dst = (isB ? bpk : apk) + (size_t)row * DIM;
    double nrm = 0.0;
#pragma unroll
    for (int k = 0; k < 4; k++) {
        int d0 = t * 4 + 1024 * k;
        float4 v = *(const float4*)(src + d0);
        nrm += (double)v.x * v.x + (double)v.y * v.y
             + (double)v.z * v.z + (double)v.w * v.w;
        int packed = 0;
        packed = __builtin_amdgcn_cvt_pk_fp8_f32(v.x, v.y, packed, false);
        packed = __builtin_amdgcn_cvt_pk_fp8_f32(v.z, v.w, packed, true);
        int c = d0 & 127;
        int s8 = c >> 3, kk = s8 >> 2, g = s8 & 3;
        int q8 = ((kk & 2) << 2) | (g << 1) | (kk & 1);
        *(int*)(dst + (d0 & ~127) + (q8 << 3) + (c & 7)) = packed;
    }
    if (isB) {
        __shared__ double red[256];
        red[t] = nrm;
        __syncthreads();
        for (int off = 128; off > 0; off >>= 1) {
            if (t < off) red[t] += red[t + off];
            __syncthreads();
        }
        if (t == 0) {
            enorms[row] = (float)red[0];
            counts[row] = 0;
        }
    }
}

// ---------------------------------------------------------------------------
// K_gemm: approx S = x·e via fp8-e4m3 MFMA. 128x128 tile, BK=128 fp8,
// 4 waves, double-buffered 2x32KB LDS, counted-vmcnt pipeline (R8-proven).
// NEW (R9): XCD-supertiled block mapping — each XCD owns bm in [x*8,x*8+8)
// and sweeps 8x8 (bm,bn) supertiles, so the ~64 blocks resident per XCD
// share a 4MB A-slice + 4MB B-slice (~L2-sized); B streams once per XCD
// instead of 8x -> staged reads become L2 hits, vmcnt stall shrinks.
// Epilogue: top-2 (key|col) per (row, 64-col slice); exact recheck downstream.
__global__ __launch_bounds__(256) void k_gemm(const char* __restrict__ apk,
                                              const char* __restrict__ bpk,
                                              const float* __restrict__ enorms,
                                              u64* __restrict__ cand) {
    __shared__ alignas(16) char lds[65536];   // 2 x (A 16KB | B 16KB)
    int b = blockIdx.x;
    int x = b & 7, l = b >> 3;                // XCD id, local index 0..511
    int bm = x * 8 + ((l >> 3) & 7);          // XCD owns 8 bm rows
    int bn = (l >> 6) * 8 + (l & 7);          // 8x8 supertile sweep
    int tid = threadIdx.x;
    int lane = tid & 63, wid = tid >> 6;
    int wm = wid >> 1, wn = wid & 1;

    // staging: 8 issues/thread/K-tile (4 A + 4 B); source pre-swizzled at 16B
    const char* srcs[8];
    unsigned lof[8];
#pragma unroll
    for (int e = 0; e < 8; e++) {
        int tile = e >> 2, q = e & 3;
        int s = q * 256 + tid;                 // 16B slot 0..1023 within tile
        int r = s >> 3;                        // row 0..127 (128B rows)
        int c16 = (s & 7) ^ (r & 7);           // inverse swizzle on source
        int row = (tile ? bn : bm) * 128 + r;
        srcs[e] = (tile ? bpk : apk) + (size_t)row * DIM + c16 * 16;
        lof[e] = tile * 16384 + q * 4096 + wid * 1024;   // + lane*16 by HW
    }

    f32x4 acc[4][4];
#pragma unroll
    for (int m = 0; m < 4; m++)
#pragma unroll
        for (int n = 0; n < 4; n++) acc[m][n] = (f32x4){0.f, 0.f, 0.f, 0.f};

    const int g = lane >> 4;                  // lane group 0..3
    const int ra = wm * 64 + (lane & 15);     // A row base (+ m*16)
    const int rb = wn * 64 + (lane & 15);     // B row base (+ n*16)

#define STAGE(buf) { _Pragma("unroll") for (int e = 0; e < 8; e++) { \
        gload16(srcs[e], &lds[(buf) * 32768u + lof[e]]); srcs[e] += 128; } }

    STAGE(0);   // prologue: tile 0 -> buf 0 (8 loads in flight)

    for (int kt = 0; kt < 32; ++kt) {
        const unsigned cur = (kt & 1) ? 32768u : 0u;
        if (kt < 31) {
            STAGE((kt & 1) ^ 1);   // next tile: 8 more in flight (16 total)
            asm volatile("s_waitcnt vmcnt(8)" ::: "memory");   // current tile landed
        } else {
            asm volatile("s_waitcnt vmcnt(0)" ::: "memory");
        }
        __builtin_amdgcn_sched_barrier(0);
        __builtin_amdgcn_s_barrier();          // all waves' current-tile loads landed
        __builtin_amdgcn_s_setprio(1);
#pragma unroll
        for (int h = 0; h < 2; h++) {
            i64x2 av[4], bv[4];
#pragma unroll
            for (int m = 0; m < 4; m++) {
                int r = ra + m * 16;
                av[m] = *(const i64x2*)&lds[cur + r * 128 + ((((h << 2) + g) ^ (r & 7)) << 4)];
            }
#pragma unroll
            for (int n = 0; n < 4; n++) {
                int r = rb + n * 16;
                bv[n] = *(const i64x2*)&lds[cur + 16384 + r * 128 + ((((h << 2) + g) ^ (r & 7)) << 4)];
            }
#pragma unroll
            for (int m = 0; m < 4; m++)
#pragma unroll
                for (int n = 0; n < 4; n++) {
                    acc[m][n] = __builtin_amdgcn_mfma_f32_16x16x32_fp8_fp8(av[m][0], bv[n][0], acc[m][n], 0, 0, 0);
                    acc[m][n] = __builtin_amdgcn_mfma_f32_16x16x32_fp8_fp8(av[m][1], bv[n][1], acc[m][n], 0, 0, 0);
                }
        }
        __builtin_amdgcn_s_setprio(0);
        __builtin_amdgcn_s_barrier();          // readers done before next STAGE overwrites
    }
#undef STAGE

    // epilogue: approx dist = ||e||^2 - 2S; keep 2 smallest per (row, 64-col slice)
    float en[4];
    int colb = bn * 128 + wn * 64 + (lane & 15);
#pragma unroll
    for (int n = 0; n < 4; n++) en[n] = enorms[colb + n * 16];
#pragma unroll
    for (int m = 0; m < 4; m++) {
#pragma unroll
        for (int reg = 0; reg < 4; reg++) {
            u64 k1 = ~0ull, k2 = ~0ull;
#pragma unroll
            for (int n = 0; n < 4; n++) {
                float d = en[n] - 2.0f * acc[m][n][reg];
                unsigned bb = __float_as_uint(d);
                unsigned key = (bb & 0x80000000u) ? ~bb : (bb | 0x80000000u);
                ins2(k1, k2, ((u64)key << 32) | (unsigned)(colb + n * 16));
            }
#pragma unroll
            for (int msk = 1; msk < 16; msk <<= 1) {
                u64 o1 = __shfl_xor(k1, msk, 64);
                u64 o2 = __shfl_xor(k2, msk, 64);
                ins2(k1, k2, o1);
                ins2(k1, k2, o2);
            }
            if ((lane & 15) == 0) {
                int rowg = bm * 128 + wm * 64 + m * 16 + ((lane >> 4) << 2) + reg;
                size_t slot = ((size_t)rowg * 64 + bn) * 2 + wn;
                ulonglong2 v; v.x = k1; v.y = k2;
                *(ulonglong2*)&cand[slot * 2] = v;
            }
        }
    }
}

// ---------------------------------------------------------------------------
// K_cand: per token, min over 256 stored entries; collect candidates within
// DELTA; exact f32 recheck (float4 loads, per-wave partials, ONE barrier);
// fused quantize-copy + loss partial + count.
__global__ __launch_bounds__(256) void k_cand(const u64* __restrict__ cand,
                                              const float* __restrict__ enorms,
                                              const float* __restrict__ inputs,
                                              const float* __restrict__ embedding,
                                              float* __restrict__ o_idx,
                                              float* __restrict__ o_quant,
                                              float* __restrict__ partials,
                                              int* __restrict__ counts) {
    int tok = blockIdx.x, t = threadIdx.x;
    int lane = t & 63, w = t >> 6;
    __shared__ u64 redu[4];
    __shared__ float redf[4];
    __shared__ float pdot[64][4];
    __shared__ int clist[64];
    __shared__ int s_cnt;
    if (t == 0) s_cnt = 0;
    u64 e = cand[(size_t)tok * 256 + t];
    u64 v = e;
#pragma unroll
    for (int msk = 1; msk < 64; msk <<= 1) {
        u64 o = __shfl_xor(v, msk, 64);
        if (o < v) v = o;
    }
    if (lane == 0) redu[w] = v;
    __syncthreads();
    u64 m01 = redu[0] < redu[1] ? redu[0] : redu[1];
    u64 m23 = redu[2] < redu[3] ? redu[2] : redu[3];
    u64 mall = m01 < m23 ? m01 : m23;
    float dmin = keyinv((unsigned)(mall >> 32));
    float myd = keyinv((unsigned)(e >> 32));
    if (myd <= dmin + DELTA) {
        int p = atomicAdd(&s_cnt, 1);
        if (p < 64) clist[p] = (int)(unsigned)(e & 0xffffffffu);
    }
    __syncthreads();
    int nc = min(s_cnt, 64);

    const float* xrow = inputs + (size_t)tok * DIM;
    float4 xr4[4];
#pragma unroll
    for (int k = 0; k < 4; k++) xr4[k] = *(const float4*)(xrow + t * 4 + 1024 * k);

    // all candidate dots first (per-wave partials, no barrier inside loop)
    for (int i = 0; i < nc; i++) {
        int c = clist[i];
        const float* erow = embedding + (size_t)c * DIM;
        float p = 0.f;
#pragma unroll
        for (int k = 0; k < 4; k++) {
            float4 e4 = *(const float4*)(erow + t * 4 + 1024 * k);
            p += xr4[k].x * e4.x + xr4[k].y * e4.y + xr4[k].z * e4.z + xr4[k].w * e4.w;
        }
#pragma unroll
        for (int msk = 1; msk < 64; msk <<= 1) p += __shfl_xor(p, msk, 64);
        if (lane == 0) pdot[i][w] = p;
    }
    __syncthreads();   // the ONE barrier

    float best = 3.4e38f;
    int bcol = 0x7fffffff;
    for (int i = 0; i < nc; i++) {
        int c = clist[i];
        float dot = (pdot[i][0] + pdot[i][1]) + (pdot[i][2] + pdot[i][3]);
        float dist = enorms[c] - 2.0f * dot;
        if (dist < best || (dist == best && c < bcol)) { best = dist; bcol = c; }
    }
    // all threads agree on bcol (identical reduced values)
    const float* eb = embedding + (size_t)bcol * DIM;
    float* qrow = o_quant + (size_t)tok * DIM;   // 4B-misaligned region: scalar stores
    float ls = 0.f;
#pragma unroll
    for (int k = 0; k < 4; k++) {
        int d = t * 4 + 1024 * k;
        float4 q4 = *(const float4*)(eb + d);
        qrow[d + 0] = q4.x; qrow[d + 1] = q4.y; qrow[d + 2] = q4.z; qrow[d + 3] = q4.w;
        float dx = q4.x - xr4[k].x, dy = q4.y - xr4[k].y;
        float dz = q4.z - xr4[k].z, dw = q4.w - xr4[k].w;
        ls += dx * dx + dy * dy + dz * dz + dw * dw;
    }
#pragma unroll
    for (int msk = 1; msk < 64; msk <<= 1) ls += __shfl_xor(ls, msk, 64);
    if (lane == 0) redf[w] = ls;
    __syncthreads();
    if (t == 0) {
        partials[tok] = (redf[0] + redf[1]) + (redf[2] + redf[3]);
        o_idx[tok] = (float)bcol;
        atomicAdd(&counts[bcol], 1);
    }
}

// ---------------------------------------------------------------------------
__global__ __launch_bounds__(1024) void k_cs(const int* __restrict__ counts,
                                             const float* __restrict__ ema_cs,
                                             float* __restrict__ o_ncs,
                                             float* __restrict__ o_perp) {
    __shared__ float red[1024];
    int t = threadIdx.x;
    float pre[8];
    float psum = 0.f, esum = 0.f;
#pragma unroll
    for (int k = 0; k < 8; k++) {
        int j = t * 8 + k;
        float c = (float)counts[j];
        float p = ema_cs[j] * 0.99f + 0.01f * c;
        pre[k] = p;
        psum += p;
        float ap = c * (1.0f / 8192.0f);
        esum += ap * logf(ap + 1e-10f);
    }
    red[t] = psum;
    __syncthreads();
    for (int off = 512; off > 0; off >>= 1) {
        if (t < off) red[t] += red[t + off];
        __syncthreads();
    }
    float n = red[0];
    __syncthreads();
    red[t] = esum;
    __syncthreads();
    for (int off = 512; off > 0; off >>= 1) {
        if (t < off) red[t] += red[t + off];
        __syncthreads();
    }
    if (t == 0) o_perp[0] = expf(-red[0]);
    float scale = n / (n + (float)VOCAB * 1e-5f);
#pragma unroll
    for (int k = 0; k < 8; k++) {
        int j = t * 8 + k;
        o_ncs[j] = (pre[k] + 1e-5f) * scale;
    }
}

// ---------------------------------------------------------------------------
__global__ __launch_bounds__(1024) void k_loss(const float* __restrict__ partials,
                                               float* __restrict__ o_loss) {
    __shared__ float red[1024];
    int t = threadIdx.x;
    float s = 0.f;
#pragma unroll
    for (int k = 0; k < 8; k++) s += partials[t * 8 + k];
    red[t] = s;
    __syncthreads();
    for (int off = 512; off > 0; off >>= 1) {
        if (t < off) red[t] += red[t + off];
        __syncthreads();
    }
    if (t == 0) o_loss[0] = 0.25f * red[0] / ((float)N_TOK * (float)DIM);
}

// ---------------------------------------------------------------------------
// K_ema: block j owns code j; ordered token list (deterministic), then
// float4-vectorized gather-sum + EMA math (scalar stores: output region
// is 4B-misaligned).
__global__ __launch_bounds__(256) void k_ema(const float* __restrict__ o_idx,
                                             const float* __restrict__ inputs,
                                             const float* __restrict__ ema_w,
                                             const float* __restrict__ o_ncs,
                                             float* __restrict__ o_neww,
                                             float* __restrict__ o_newemb) {
    int j = blockIdx.x, t = threadIdx.x;
    __shared__ int scan[256];
    __shared__ int list[256];
    __shared__ int s_total;
    int c = 0;
    for (int k = 0; k < 32; k++) {
        int tok = t * 32 + k;
        if ((int)o_idx[tok] == j) c++;
    }
    scan[t] = c;
    __syncthreads();
    for (int off = 1; off < 256; off <<= 1) {
        int add = (t >= off) ? scan[t - off] : 0;
        __syncthreads();
        scan[t] += add;
        __syncthreads();
    }
    int excl = scan[t] - c;
    if (t == 255) s_total = scan[255];
    __syncthreads();
    int pos = excl;
    for (int k = 0; k < 32; k++) {
        int tok = t * 32 + k;
        if ((int)o_idx[tok] == j && pos < 256) list[pos++] = tok;
    }
    __syncthreads();
    int total = s_total;
    float nc = o_ncs[j];
    size_t rowoff = (size_t)j * DIM;
#pragma unroll
    for (int k = 0; k < 4; k++) {
        int d = t * 4 + 1024 * k;
        float sx = 0.f, sy = 0.f, sz = 0.f, sw = 0.f;
        for (int q = 0; q < total; q++) {
            float4 v = *(const float4*)(inputs + (size_t)list[q] * DIM + d);
            sx += v.x; sy += v.y; sz += v.z; sw += v.w;
        }
        float4 w4 = *(const float4*)(ema_w + rowoff + d);
        float w0 = w4.x * 0.99f + 0.01f * sx;
        float w1 = w4.y * 0.99f + 0.01f * sy;
        float w2 = w4.z * 0.99f + 0.01f * sz;
        float w3 = w4.w * 0.99f + 0.01f * sw;
        o_neww[rowoff + d + 0] = w0; o_newemb[rowoff + d + 0] = w0 / nc;
        o_neww[rowoff + d + 1] = w1; o_newemb[rowoff + d + 1] = w1 / nc;
        o_neww[rowoff + d + 2] = w2; o_newemb[rowoff + d + 2] = w2 / nc;
        o_neww[rowoff + d + 3] = w3; o_newemb[rowoff + d + 3] = w3 / nc;
    }
}

// ---------------------------------------------------------------------------
extern "C" void kernel_launch(void* const* d_in, const int* in_sizes, int n_in,
                              void* d_out, int out_size, void* d_ws, size_t ws_size,
                              hipStream_t stream) {
    const float* inputs    = (const float*)d_in[0];
    const float* embedding = (const float*)d_in[1];
    const float* ema_w     = (const float*)d_in[2];
    const float* ema_cs    = (const float*)d_in[3];

    float* out = (float*)d_out;
    char* base = (char*)d_out;

    // scratch carved from d_out (lifetime-checked):
    // apk/bpk (fp8, 32MB each) dead after k_gemm; cand/enorms/counts/partials
    // parked inside o_neww region (written only by k_ema, last kernel).
    char* apk       = base;                            // [0, 32M)
    char* bpk       = base + 33554432;                 // [32M, 64M)
    u64* cand       = (u64*)(base + 167772160);        // 16 MB, dead after k_cand
    float* enorms   = (float*)(base + 184549376);      // 32 KB, dead after k_cand
    int* counts     = (int*)(base + 184582144);        // 32 KB, dead after k_cs
    float* partials = (float*)(base + 184614912);      // 32 KB, dead after k_loss

    // output regions (element offsets, return order)
    float* o_loss   = out;                 // [1]
    float* o_quant  = out + 1;             // [8192*4096]
    float* o_perp   = out + 33554433;      // [1]
    float* o_idx    = out + 33554434;      // [8192]
    float* o_ncs    = out + 33562626;      // [8192]
    float* o_neww   = out + 33570818;      // [8192*4096]
    float* o_newemb = out + 67125250;      // [8192*4096]

    k_pack<<<dim3(N_TOK + VOCAB), dim3(256), 0, stream>>>(inputs, embedding, apk, bpk,
                                                          enorms, counts);
    k_gemm<<<dim3(4096), dim3(256), 0, stream>>>(apk, bpk, enorms, cand);
    k_cand<<<dim3(N_TOK), dim3(256), 0, stream>>>(cand, enorms, inputs, embedding,
                                                  o_idx, o_quant, partials, counts);
    k_cs<<<dim3(1), dim3(1024), 0, stream>>>(counts, ema_cs, o_ncs, o_perp);
    k_loss<<<dim3(1), dim3(1024), 0, stream>>>(partials, o_loss);
    k_ema<<<dim3(VOCAB), dim3(256), 0, stream>>>(o_idx, inputs, ema_w, o_ncs, o_neww, o_newemb);
}